// Round 8
// baseline (274.348 us; speedup 1.0000x reference)
//
#include <hip/hip_runtime.h>
#include <hip/hip_bf16.h>

// Problem constants (fixed by reference)
#define N_NODES   16384
#define DEG       16
#define EDGES     262144          // N_NODES*DEG
#define HC        256             // HEADS*OUT_C
#define KDIM      16384           // 64 nodes * 256 feat
#define NEG_SLOPE 0.2f

typedef __attribute__((ext_vector_type(8))) short short8;   // 8 bf16
typedef __attribute__((ext_vector_type(4))) float floatx4;

static __device__ __forceinline__ unsigned short f2bf(float f) {
    union { __hip_bfloat16 h; unsigned short u; } c;
    c.h = __float2bfloat16(f);          // RNE
    return c.u;
}
static __device__ __forceinline__ unsigned int packbf2(float lo, float hi) {
    union { __hip_bfloat162 h2; unsigned int u; } c;
    c.h2 = __float22bfloat162_rn(make_float2(lo, hi));   // v_cvt_pk_bf16_f32
    return c.u;
}

// DPP row_shr add chain {1,2,4,8}: lane l15==15 holds the 16-lane sum.
template <int CTRL>
static __device__ __forceinline__ float dpp_add(float v) {
    int x = __builtin_amdgcn_update_dpp(0, __float_as_int(v), CTRL, 0xF, 0xF, true);
    return v + __int_as_float(x);
}

// ---- mean(edge_attr) partial sums: 256 blocks x 1024 rows -----------------
__global__ __launch_bounds__(256) void k_ea_part(const float* __restrict__ ea,
                                                 float* __restrict__ part) {
    __shared__ float s[256];
    int b = blockIdx.x, t = threadIdx.x;
    int col = t & 15, r0 = t >> 4;
    const float* base = ea + (size_t)b * 1024 * 16;
    float acc = 0.f;
    for (int r = r0; r < 1024; r += 16) acc += base[r * 16 + col];
    s[t] = acc; __syncthreads();
    for (int off = 128; off >= 16; off >>= 1) {
        if (t < off) s[t] += s[t + off];
        __syncthreads();
    }
    if (t < 16) part[b * 16 + t] = s[t];
}

// ---- finish mean + ee_self = mean_ea @ W_e (parallel, 2-level tree) --------
__global__ __launch_bounds__(256) void k_ea_finish(const float* __restrict__ part,
                                                   const float* __restrict__ We,
                                                   float* __restrict__ eeself) {
    __shared__ float ps[16][16];     // [b-group][col]
    __shared__ float mean[16];
    int t = threadIdx.x;
    int col = t & 15, bg = t >> 4;   // 16 b-groups x 16 cols
    float a = 0.f;
    #pragma unroll
    for (int i = 0; i < 16; ++i)     // independent strided loads
        a += part[(bg + i * 16) * 16 + col];
    ps[bg][col] = a;
    __syncthreads();
    if (t < 16) {                    // final 16-add per column
        float m = 0.f;
        #pragma unroll
        for (int i = 0; i < 16; ++i) m += ps[i][t];
        mean[t] = m * (1.f / (float)EDGES);
    }
    __syncthreads();
    float acc = 0.f;
    #pragma unroll
    for (int d = 0; d < 16; ++d) acc += mean[d] * We[d * 256 + t];
    eeself[t] = acc;
}

// ---- xl|xr via MFMA: (16384 x 128) @ (128 x 512) ---------------------------
__global__ __launch_bounds__(256) void k_xlr2(const float* __restrict__ x,
                                              const float* __restrict__ Wl,
                                              const float* __restrict__ Wr,
                                              float* __restrict__ xl,
                                              float* __restrict__ xr) {
    __shared__ unsigned short As[64][40];   // [row][k] bf16
    __shared__ unsigned int   Bs[128][18];  // [col][kpair]
    unsigned int* As32 = (unsigned int*)&As[0][0];

    int t = threadIdx.x;
    int wave = t >> 6, lane = t & 63;
    int l15 = lane & 15, lk = lane >> 4;
    int wm = wave >> 1, wn = wave & 1;
    int m0 = blockIdx.x * 64;
    int n0 = blockIdx.y * 128;
    const float* Wsel = (n0 < 256) ? Wl : Wr;
    int bc = n0 & 255;

    floatx4 acc[2][4];
    #pragma unroll
    for (int i = 0; i < 2; ++i)
        #pragma unroll
        for (int j = 0; j < 4; ++j)
            acc[i][j] = (floatx4)(0.f);

    int ar = t >> 2, ac = t & 3;
    int bkp = t >> 4, bcc = t & 15;

    for (int k0 = 0; k0 < 128; k0 += 32) {
        __syncthreads();
        {   // stage A: x[m0+r][k0 + ac*8 .. +7] -> bf16
            const float* gp = x + (size_t)(m0 + ar) * 128 + k0 + ac * 8;
            float4 v0 = *(const float4*)gp;
            float4 v1 = *(const float4*)(gp + 4);
            As32[ar * 20 + ac * 4 + 0] = packbf2(v0.x, v0.y);
            As32[ar * 20 + ac * 4 + 1] = packbf2(v0.z, v0.w);
            As32[ar * 20 + ac * 4 + 2] = packbf2(v1.x, v1.y);
            As32[ar * 20 + ac * 4 + 3] = packbf2(v1.z, v1.w);
        }
        {   // stage B
            const float* wp = Wsel + (size_t)(k0 + 2 * bkp) * 256 + bc + bcc * 8;
            float4 r0a = *(const float4*)wp;
            float4 r0b = *(const float4*)(wp + 4);
            float4 r1a = *(const float4*)(wp + 256);
            float4 r1b = *(const float4*)(wp + 260);
            Bs[bcc * 8 + 0][bkp] = packbf2(r0a.x, r1a.x);
            Bs[bcc * 8 + 1][bkp] = packbf2(r0a.y, r1a.y);
            Bs[bcc * 8 + 2][bkp] = packbf2(r0a.z, r1a.z);
            Bs[bcc * 8 + 3][bkp] = packbf2(r0a.w, r1a.w);
            Bs[bcc * 8 + 4][bkp] = packbf2(r0b.x, r1b.x);
            Bs[bcc * 8 + 5][bkp] = packbf2(r0b.y, r1b.y);
            Bs[bcc * 8 + 6][bkp] = packbf2(r0b.z, r1b.z);
            Bs[bcc * 8 + 7][bkp] = packbf2(r0b.w, r1b.w);
        }
        __syncthreads();
        short8 a[2], b[4];
        #pragma unroll
        for (int mi = 0; mi < 2; ++mi)
            a[mi] = *(const short8*)&As[wm * 32 + mi * 16 + l15][lk * 8];
        #pragma unroll
        for (int ni = 0; ni < 4; ++ni) {
            int nr = wn * 64 + ni * 16 + l15;
            union { uint2 u[2]; short8 v; } bb;
            bb.u[0] = *(const uint2*)&Bs[nr][lk * 4];
            bb.u[1] = *(const uint2*)&Bs[nr][lk * 4 + 2];
            b[ni] = bb.v;
        }
        #pragma unroll
        for (int mi = 0; mi < 2; ++mi)
            #pragma unroll
            for (int ni = 0; ni < 4; ++ni)
                acc[mi][ni] = __builtin_amdgcn_mfma_f32_16x16x32_bf16(a[mi], b[ni], acc[mi][ni], 0, 0, 0);
    }

    #pragma unroll
    for (int mi = 0; mi < 2; ++mi) {
        #pragma unroll
        for (int ni = 0; ni < 4; ++ni) {
            int n = n0 + wn * 64 + ni * 16 + l15;
            #pragma unroll
            for (int r = 0; r < 4; ++r) {
                int node = m0 + wm * 32 + mi * 16 + lk * 4 + r;
                if (n0 < 256) xl[(size_t)node * 256 + n]         = acc[mi][ni][r];
                else          xr[(size_t)node * 256 + (n - 256)] = acc[mi][ni][r];
            }
        }
    }
}

// ---- fused GAT attention v5: permuted LDS layout, vectorized DS traffic ----
__global__ __launch_bounds__(256) void k_attn(const int* __restrict__ ei,
                                              const float* __restrict__ ea,
                                              const float* __restrict__ eeself,
                                              const float* __restrict__ att,
                                              const float* __restrict__ We,
                                              const float* __restrict__ xl,
                                              const float* __restrict__ xr,
                                              const float* __restrict__ bg,
                                              unsigned short* __restrict__ hb) {
    __shared__ float xlS[64][68];    // permuted cols, pitch 68
    __shared__ float xrS[64][68];
    __shared__ float lgS[1088];
    __shared__ int   srcS[1024];

    int t = threadIdx.x;
    int g = blockIdx.x >> 2, h = blockIdx.x & 3;
    int hc0 = h * 64;

    {   // stage xl/xr head slices into PERMUTED layout
        int n = t >> 2, q4 = t & 3;
        const float* xlp = xl + ((size_t)(g * 64 + n)) * 256 + hc0 + q4 * 16;
        const float* xrp = xr + ((size_t)(g * 64 + n)) * 256 + hc0 + q4 * 16;
        #pragma unroll
        for (int i = 0; i < 4; ++i) {
            float4 vl = *(const float4*)(xlp + i * 4);
            float4 vr = *(const float4*)(xrp + i * 4);
            xlS[n][(i * 4 + 0) * 4 + q4] = vl.x;
            xlS[n][(i * 4 + 1) * 4 + q4] = vl.y;
            xlS[n][(i * 4 + 2) * 4 + q4] = vl.z;
            xlS[n][(i * 4 + 3) * 4 + q4] = vl.w;
            xrS[n][(i * 4 + 0) * 4 + q4] = vr.x;
            xrS[n][(i * 4 + 1) * 4 + q4] = vr.y;
            xrS[n][(i * 4 + 2) * 4 + q4] = vr.z;
            xrS[n][(i * 4 + 3) * 4 + q4] = vr.w;
        }
    }
    {   // stage local src indices
        int4 v = *(const int4*)(ei + (size_t)g * 1024 + t * 4);
        srcS[t * 4 + 0] = v.x & 63;
        srcS[t * 4 + 1] = v.y & 63;
        srcS[t * 4 + 2] = v.z & 63;
        srcS[t * 4 + 3] = v.w & 63;
    }

    int wave = t >> 6, lane = t & 63;
    int q = lane >> 4, l15 = lane & 15;

    short8 wf[4];
    float  attv[4];
    #pragma unroll
    for (int nt = 0; nt < 4; ++nt) {
        attv[nt] = att[hc0 + nt * 16 + l15];
        if (q < 2) {
            const float* wp = We + (size_t)(q * 8) * 256 + hc0 + nt * 16 + l15;
            float w0 = wp[0*256], w1 = wp[1*256], w2 = wp[2*256], w3 = wp[3*256];
            float w4 = wp[4*256], w5 = wp[5*256], w6 = wp[6*256], w7 = wp[7*256];
            union { unsigned int u[4]; short8 v; } bb;
            bb.u[0] = packbf2(w0, w1);
            bb.u[1] = packbf2(w2, w3);
            bb.u[2] = packbf2(w4, w5);
            bb.u[3] = packbf2(w6, w7);
            wf[nt] = bb.v;
        } else {
            wf[nt] = (short8)0;
        }
    }
    __syncthreads();

    for (int b = wave; b < 16; b += 4) {
        short8 af[4];
        #pragma unroll
        for (int mt = 0; mt < 4; ++mt) {
            if (q < 2) {
                const float* ep = ea + ((size_t)(g * 1024 + b * 64 + mt * 16 + l15)) * 16 + q * 8;
                float4 v0 = *(const float4*)ep;
                float4 v1 = *(const float4*)(ep + 4);
                union { unsigned int u[4]; short8 v; } bb;
                bb.u[0] = packbf2(v0.x, v0.y);
                bb.u[1] = packbf2(v0.z, v0.w);
                bb.u[2] = packbf2(v1.x, v1.y);
                bb.u[3] = packbf2(v1.z, v1.w);
                af[mt] = bb.v;
            } else {
                af[mt] = (short8)0;
            }
        }
        floatx4 acc[4][4];
        #pragma unroll
        for (int mt = 0; mt < 4; ++mt)
            #pragma unroll
            for (int nt = 0; nt < 4; ++nt)
                acc[mt][nt] = __builtin_amdgcn_mfma_f32_16x16x32_bf16(af[mt], wf[nt], (floatx4)(0.f), 0, 0, 0);

        #pragma unroll
        for (int mt = 0; mt < 4; ++mt) {
            float4 xrv = *(const float4*)&xrS[b * 4 + mt][l15 * 4];
            int4  s4  = *(const int4*)&srcS[b * 64 + mt * 16 + q * 4];
            int sr[4] = {s4.x, s4.y, s4.z, s4.w};
            float lsum[4];
            #pragma unroll
            for (int r = 0; r < 4; ++r) {
                float4 xlv = *(const float4*)&xlS[sr[r]][l15 * 4];
                float f, acc_sum = 0.f;
                f = acc[mt][0][r] + xlv.x + xrv.x; f = fmaxf(f, NEG_SLOPE * f); acc_sum += f * attv[0];
                f = acc[mt][1][r] + xlv.y + xrv.y; f = fmaxf(f, NEG_SLOPE * f); acc_sum += f * attv[1];
                f = acc[mt][2][r] + xlv.z + xrv.z; f = fmaxf(f, NEG_SLOPE * f); acc_sum += f * attv[2];
                f = acc[mt][3][r] + xlv.w + xrv.w; f = fmaxf(f, NEG_SLOPE * f); acc_sum += f * attv[3];
                lsum[r] = acc_sum;
            }
            #pragma unroll
            for (int r = 0; r < 4; ++r) {
                float v = lsum[r];
                v = dpp_add<0x111>(v);
                v = dpp_add<0x112>(v);
                v = dpp_add<0x114>(v);
                v = dpp_add<0x118>(v);
                if (l15 == 15) lgS[b * 64 + mt * 16 + q * 4 + r] = v;
            }
        }
    }

    {   // self-loop batch (permuted indexing)
        int n = wave * 16 + l15;
        float sum = 0.f;
        const float* eep = eeself + hc0 + q * 16;
        const float* ap  = att + hc0 + q * 16;
        #pragma unroll
        for (int i = 0; i < 4; ++i) {
            float4 ev = *(const float4*)(eep + i * 4);
            float4 av = *(const float4*)(ap + i * 4);
            #pragma unroll
            for (int j = 0; j < 4; ++j) {
                int p = (i * 4 + j) * 4 + q;
                float e = (j == 0) ? ev.x : (j == 1) ? ev.y : (j == 2) ? ev.z : ev.w;
                float a = (j == 0) ? av.x : (j == 1) ? av.y : (j == 2) ? av.z : av.w;
                float f = xlS[n][p] + xrS[n][p] + e;
                f = fmaxf(f, NEG_SLOPE * f);
                sum += f * a;
            }
        }
        sum += __shfl_xor(sum, 16);
        sum += __shfl_xor(sum, 32);
        if (q == 0) lgS[1024 + n] = sum;
    }
    __syncthreads();

    if (t < 64) {
        float lg[17];
        #pragma unroll
        for (int j = 0; j < 16; ++j) lg[j] = lgS[t * 16 + j];
        lg[16] = lgS[1024 + t];
        float m = lg[0];
        #pragma unroll
        for (int j = 1; j < 17; ++j) m = fmaxf(m, lg[j]);
        float ex[17], ssum = 0.f;
        #pragma unroll
        for (int j = 0; j < 17; ++j) { ex[j] = __expf(lg[j] - m); ssum += ex[j]; }
        float inv = 1.f / (17.f * ssum);
        #pragma unroll
        for (int j = 0; j < 16; ++j) lgS[t * 16 + j] = ex[j] * inv;
        lgS[1024 + t] = ex[16] * inv;
    }
    __syncthreads();

    {   // aggregation: lane = logical col c; permuted read position pc
        int c = lane;
        int pc = (c & 15) * 4 + (c >> 4);
        float bgv = bg[hc0 + c];
        for (int n = wave * 16; n < wave * 16 + 16; ++n) {
            float4 al0 = *(const float4*)&lgS[n * 16];
            float4 al1 = *(const float4*)&lgS[n * 16 + 4];
            float4 al2 = *(const float4*)&lgS[n * 16 + 8];
            float4 al3 = *(const float4*)&lgS[n * 16 + 12];
            int4  s0  = *(const int4*)&srcS[n * 16];
            int4  s1  = *(const int4*)&srcS[n * 16 + 4];
            int4  s2  = *(const int4*)&srcS[n * 16 + 8];
            int4  s3  = *(const int4*)&srcS[n * 16 + 12];
            float a0 = lgS[1024 + n] * xlS[n][pc];
            float a1 = 0.f;
            a0 += al0.x * xlS[s0.x][pc];  a1 += al0.y * xlS[s0.y][pc];
            a0 += al0.z * xlS[s0.z][pc];  a1 += al0.w * xlS[s0.w][pc];
            a0 += al1.x * xlS[s1.x][pc];  a1 += al1.y * xlS[s1.y][pc];
            a0 += al1.z * xlS[s1.z][pc];  a1 += al1.w * xlS[s1.w][pc];
            a0 += al2.x * xlS[s2.x][pc];  a1 += al2.y * xlS[s2.y][pc];
            a0 += al2.z * xlS[s2.z][pc];  a1 += al2.w * xlS[s2.w][pc];
            a0 += al3.x * xlS[s3.x][pc];  a1 += al3.y * xlS[s3.y][pc];
            a0 += al3.z * xlS[s3.z][pc];  a1 += al3.w * xlS[s3.w][pc];
            float val = a0 + a1 + bgv;
            hb[((size_t)(g * 64 + n)) * 256 + hc0 + c] = f2bf(val);
        }
    }
}

// ---- big GEMM v7: 1-iter-deep prefetch, counted vmcnt, unroll-2 ------------
__global__ __launch_bounds__(256) void k_gemm(const unsigned short* __restrict__ hb,
                                              const float* __restrict__ W,
                                              float* __restrict__ parts) {
    __shared__ unsigned short As[2][256 * 32];
    __shared__ unsigned int   Bs[2][64][18];

    int t = threadIdx.x;
    int wave = t >> 6, lane = t & 63;
    int l15 = lane & 15, lk = lane >> 4;
    int n0 = blockIdx.x * 64;
    int s  = blockIdx.y;
    int kbase = s * 2048;

    floatx4 acc[4][4];
    #pragma unroll
    for (int i = 0; i < 4; ++i)
        #pragma unroll
        for (int j = 0; j < 4; ++j)
            acc[i][j] = (floatx4)(0.f);

    int gc = ((lane & 3) - ((lane >> 3) & 3)) & 3;
    const unsigned short* a_src =
        hb + (size_t)(wave * 64 + (lane >> 2)) * KDIM + kbase + gc * 8;
    int ap_off[4];
    #pragma unroll
    for (int mi = 0; mi < 4; ++mi)
        ap_off[mi] = (wave * 64 + mi * 16 + l15) * 32 + (((lk + (l15 >> 1)) & 3) * 8);

    int bkp = t >> 4;
    int bc8 = t & 15;
    const float* b_src = W + (size_t)(kbase + 2 * bkp) * 4096 + n0 + bc8 * 4;

    #define ISSUE_A(step, buf)                                                   \
        {                                                                        \
            const unsigned short* gp_ = a_src + (size_t)(step) * 32;             \
            _Pragma("unroll")                                                    \
            for (int i_ = 0; i_ < 4; ++i_) {                                     \
                __builtin_amdgcn_global_load_lds(                                \
                    (const __attribute__((address_space(1))) unsigned int*)      \
                        (gp_ + (size_t)i_ * 16 * KDIM),                          \
                    (__attribute__((address_space(3))) unsigned int*)            \
                        &As[buf][(wave * 64 + i_ * 16) * 32],                    \
                    16, 0, 0);                                                   \
            }                                                                    \
        }
    #define LOAD_B(step, r0, r1)                                                 \
        {                                                                        \
            const float* wp_ = b_src + (size_t)(step) * 32 * 4096;               \
            r0 = *(const float4*)wp_;                                            \
            r1 = *(const float4*)(wp_ + 4096);                                   \
        }
    #define WRITE_B(buf, r0, r1)                                                 \
        {                                                                        \
            Bs[buf][bc8 * 4 + 0][bkp] = packbf2(r0.x, r1.x);                     \
            Bs[buf][bc8 * 4 + 1][bkp] = packbf2(r0.y, r1.y);                     \
            Bs[buf][bc8 * 4 + 2][bkp] = packbf2(r0.z, r1.z);                     \
            Bs[buf][bc8 * 4 + 3][bkp] = packbf2(r0.w, r1.w);                     \
        }
    #define COMPUTE(abuf, bbuf)                                                  \
        {                                                                        \
            short8 a_[4], b_[4];                                                 \
            _Pragma("unroll")                                                    \
            for (int mi = 0; mi < 4; ++mi)                                       \
                a_[mi] = *(const short8*)&As[abuf][ap_off[mi]];                  \
            _Pragma("unroll")                                                    \
            for (int ni = 0; ni < 4; ++ni) {                                     \
                int nr_ = ni * 16 + l15;                                         \
                union { uint2 u[2]; short8 v; } bb_;                             \
                bb_.u[0] = *(const uint2*)&Bs[bbuf][nr_][lk * 4];                \
                bb_.u[1] = *(const uint2*)&Bs[bbuf][nr_][lk * 4 + 2];            \
                b_[ni] = bb_.v;                                                  \
            }                                                                    \
            __builtin_amdgcn_s_setprio(1);                                       \
            _Pragma("unroll")                                                    \
            for (int mi = 0; mi < 4; ++mi)                                       \
                _Pragma("unroll")                                                \
                for (int ni = 0; ni < 4; ++ni)                                   \
                    acc[mi][ni] = __builtin_amdgcn_mfma_f32_16x16x32_bf16(       \
                        a_[mi], b_[ni], acc[mi][ni], 0, 0, 0);                   \
            __builtin_amdgcn_s_setprio(0);                                       \
        }
    #define VMCNT(n) __builtin_amdgcn_sched_barrier(0);                          \
                     asm volatile("s_waitcnt vmcnt(" #n ")" ::: "memory");       \
                     __builtin_amdgcn_sched_barrier(0)
    #define LGKM0    asm volatile("s_waitcnt lgkmcnt(0)" ::: "memory");          \
                     __builtin_amdgcn_sched_barrier(0)

    float4 e0, e1, o0, o1;

    ISSUE_A(0, 0);
    LOAD_B(0, e0, e1);
    LOAD_B(1, o0, o1);
    VMCNT(2);
    WRITE_B(0, e0, e1);
    LGKM0;
    __builtin_amdgcn_s_barrier();

    for (int j = 0; j < 62; j += 2) {
        ISSUE_A(j + 1, 1);
        LOAD_B(j + 2, e0, e1);
        VMCNT(8);
        COMPUTE(0, 0);
        VMCNT(6);
        WRITE_B(1, o0, o1);
        LGKM0;
        __builtin_amdgcn_s_barrier();
        ISSUE_A(j + 2, 0);
        LOAD_B(j + 3, o0, o1);
        VMCNT(8);
        COMPUTE(1, 1);
        VMCNT(6);
        WRITE_B(0, e0, e1);
        LGKM0;
        __builtin_amdgcn_s_barrier();
    }
    {
        ISSUE_A(63, 1);
        VMCNT(6);
        COMPUTE(0, 0);
        VMCNT(4);
        WRITE_B(1, o0, o1);
        LGKM0;
        __builtin_amdgcn_s_barrier();
    }
    VMCNT(0);
    COMPUTE(1, 1);

    #undef ISSUE_A
    #undef LOAD_B
    #undef WRITE_B
    #undef COMPUTE
    #undef VMCNT
    #undef LGKM0

    float* dst = parts + (size_t)s * (256 * 4096);
    #pragma unroll
    for (int mi = 0; mi < 4; ++mi) {
        #pragma unroll
        for (int ni = 0; ni < 4; ++ni) {
            int col = n0 + ni * 16 + l15;
            #pragma unroll
            for (int r = 0; r < 4; ++r) {
                int row = wave * 64 + mi * 16 + lk * 4 + r;
                dst[(size_t)row * 4096 + col] = acc[mi][ni][r];
            }
        }
    }
}

// ---- reduce partials + bias -> d_out ---------------------------------------
__global__ __launch_bounds__(256) void k_reduce(const float* __restrict__ parts,
                                                const float* __restrict__ linb,
                                                float* __restrict__ out) {
    int idx = blockIdx.x * 256 + threadIdx.x;
    float v = linb[idx & 4095];
    #pragma unroll
    for (int s = 0; s < 8; ++s) v += parts[(size_t)s * (256 * 4096) + idx];
    out[idx] = v;
}

extern "C" void kernel_launch(void* const* d_in, const int* in_sizes, int n_in,
                              void* d_out, int out_size, void* d_ws, size_t ws_size,
                              hipStream_t stream) {
    (void)in_sizes; (void)n_in; (void)out_size; (void)ws_size;
    const float* x   = (const float*)d_in[0];
    const int*   ei  = (const int*)d_in[1];
    const float* ea  = (const float*)d_in[2];
    /* d_in[3] = batch (unused, fixed layout) */
    const float* Wl  = (const float*)d_in[4];
    const float* Wr  = (const float*)d_in[5];
    const float* We  = (const float*)d_in[6];
    const float* att = (const float*)d_in[7];
    const float* bg  = (const float*)d_in[8];
    const float* W   = (const float*)d_in[9];
    const float* lb  = (const float*)d_in[10];
    float* out = (float*)d_out;

    char* p = (char*)d_ws;
    float* xl           = (float*)p;          p += 16777216;           // 16384x256 f32
    float* xr           = (float*)p;          p += 16777216;
    unsigned short* hb  = (unsigned short*)p; p += 8388608;            // 16384x256 bf16
    float* parts        = (float*)p;          p += 33554432;           // 8x256x4096 f32
    float* parts2       = (float*)p;          p += 33554432;           // MEASUREMENT scratch
    float* eapart       = (float*)p;          p += 16384;              // 256x16
    float* eeself       = (float*)p;          p += 1024;               // 256

    k_ea_part  <<<256,  256, 0, stream>>>(ea, eapart);
    k_ea_finish<<<1,    256, 0, stream>>>(eapart, We, eeself);
    k_xlr2     <<<dim3(256, 4), 256, 0, stream>>>(x, Wl, Wr, xl, xr);
    k_attn     <<<1024, 256, 0, stream>>>(ei, ea, eeself, att, We, xl, xr, bg, hb);
    // MEASUREMENT: duplicate gemm into scratch; Delta(total) vs R7 = gemm cost.
    k_gemm     <<<dim3(64, 8), 256, 0, stream>>>(hb, W, parts2);
    k_gemm     <<<dim3(64, 8), 256, 0, stream>>>(hb, W, parts);
    k_reduce   <<<4096, 256, 0, stream>>>(parts, lb, out);
}

// Round 9
// 229.983 us; speedup vs baseline: 1.1929x; 1.1929x over previous
//
#include <hip/hip_runtime.h>
#include <hip/hip_bf16.h>

// Problem constants (fixed by reference)
#define N_NODES   16384
#define DEG       16
#define EDGES     262144          // N_NODES*DEG
#define HC        256             // HEADS*OUT_C
#define KDIM      16384           // 64 nodes * 256 feat
#define NEG_SLOPE 0.2f

typedef __attribute__((ext_vector_type(8))) short short8;   // 8 bf16
typedef __attribute__((ext_vector_type(4))) float floatx4;

static __device__ __forceinline__ unsigned short f2bf(float f) {
    union { __hip_bfloat16 h; unsigned short u; } c;
    c.h = __float2bfloat16(f);          // RNE
    return c.u;
}
static __device__ __forceinline__ unsigned int packbf2(float lo, float hi) {
    union { __hip_bfloat162 h2; unsigned int u; } c;
    c.h2 = __float22bfloat162_rn(make_float2(lo, hi));   // v_cvt_pk_bf16_f32
    return c.u;
}

// DPP row_shr add chain {1,2,4,8}: lane l15==15 holds the 16-lane sum.
template <int CTRL>
static __device__ __forceinline__ float dpp_add(float v) {
    int x = __builtin_amdgcn_update_dpp(0, __float_as_int(v), CTRL, 0xF, 0xF, true);
    return v + __int_as_float(x);
}

// ---- mean(edge_attr) partial sums: 256 blocks x 1024 rows -----------------
__global__ __launch_bounds__(256) void k_ea_part(const float* __restrict__ ea,
                                                 float* __restrict__ part) {
    __shared__ float s[256];
    int b = blockIdx.x, t = threadIdx.x;
    int col = t & 15, r0 = t >> 4;
    const float* base = ea + (size_t)b * 1024 * 16;
    float acc = 0.f;
    for (int r = r0; r < 1024; r += 16) acc += base[r * 16 + col];
    s[t] = acc; __syncthreads();
    for (int off = 128; off >= 16; off >>= 1) {
        if (t < off) s[t] += s[t + off];
        __syncthreads();
    }
    if (t < 16) part[b * 16 + t] = s[t];
}

// ---- finish mean + ee_self = mean_ea @ W_e (parallel, 2-level tree) --------
__global__ __launch_bounds__(256) void k_ea_finish(const float* __restrict__ part,
                                                   const float* __restrict__ We,
                                                   float* __restrict__ eeself) {
    __shared__ float ps[16][16];     // [b-group][col]
    __shared__ float mean[16];
    int t = threadIdx.x;
    int col = t & 15, bg = t >> 4;   // 16 b-groups x 16 cols
    float a = 0.f;
    #pragma unroll
    for (int i = 0; i < 16; ++i)
        a += part[(bg + i * 16) * 16 + col];
    ps[bg][col] = a;
    __syncthreads();
    if (t < 16) {
        float m = 0.f;
        #pragma unroll
        for (int i = 0; i < 16; ++i) m += ps[i][t];
        mean[t] = m * (1.f / (float)EDGES);
    }
    __syncthreads();
    float acc = 0.f;
    #pragma unroll
    for (int d = 0; d < 16; ++d) acc += mean[d] * We[d * 256 + t];
    eeself[t] = acc;
}

// ---- xl|xr via MFMA: (16384 x 128) @ (128 x 512) ---------------------------
__global__ __launch_bounds__(256) void k_xlr2(const float* __restrict__ x,
                                              const float* __restrict__ Wl,
                                              const float* __restrict__ Wr,
                                              float* __restrict__ xl,
                                              float* __restrict__ xr) {
    __shared__ unsigned short As[64][40];   // [row][k] bf16
    __shared__ unsigned int   Bs[128][18];  // [col][kpair]
    unsigned int* As32 = (unsigned int*)&As[0][0];

    int t = threadIdx.x;
    int wave = t >> 6, lane = t & 63;
    int l15 = lane & 15, lk = lane >> 4;
    int wm = wave >> 1, wn = wave & 1;
    int m0 = blockIdx.x * 64;
    int n0 = blockIdx.y * 128;
    const float* Wsel = (n0 < 256) ? Wl : Wr;
    int bc = n0 & 255;

    floatx4 acc[2][4];
    #pragma unroll
    for (int i = 0; i < 2; ++i)
        #pragma unroll
        for (int j = 0; j < 4; ++j)
            acc[i][j] = (floatx4)(0.f);

    int ar = t >> 2, ac = t & 3;
    int bkp = t >> 4, bcc = t & 15;

    for (int k0 = 0; k0 < 128; k0 += 32) {
        __syncthreads();
        {   // stage A: x[m0+r][k0 + ac*8 .. +7] -> bf16
            const float* gp = x + (size_t)(m0 + ar) * 128 + k0 + ac * 8;
            float4 v0 = *(const float4*)gp;
            float4 v1 = *(const float4*)(gp + 4);
            As32[ar * 20 + ac * 4 + 0] = packbf2(v0.x, v0.y);
            As32[ar * 20 + ac * 4 + 1] = packbf2(v0.z, v0.w);
            As32[ar * 20 + ac * 4 + 2] = packbf2(v1.x, v1.y);
            As32[ar * 20 + ac * 4 + 3] = packbf2(v1.z, v1.w);
        }
        {   // stage B
            const float* wp = Wsel + (size_t)(k0 + 2 * bkp) * 256 + bc + bcc * 8;
            float4 r0a = *(const float4*)wp;
            float4 r0b = *(const float4*)(wp + 4);
            float4 r1a = *(const float4*)(wp + 256);
            float4 r1b = *(const float4*)(wp + 260);
            Bs[bcc * 8 + 0][bkp] = packbf2(r0a.x, r1a.x);
            Bs[bcc * 8 + 1][bkp] = packbf2(r0a.y, r1a.y);
            Bs[bcc * 8 + 2][bkp] = packbf2(r0a.z, r1a.z);
            Bs[bcc * 8 + 3][bkp] = packbf2(r0a.w, r1a.w);
            Bs[bcc * 8 + 4][bkp] = packbf2(r0b.x, r1b.x);
            Bs[bcc * 8 + 5][bkp] = packbf2(r0b.y, r1b.y);
            Bs[bcc * 8 + 6][bkp] = packbf2(r0b.z, r1b.z);
            Bs[bcc * 8 + 7][bkp] = packbf2(r0b.w, r1b.w);
        }
        __syncthreads();
        short8 a[2], b[4];
        #pragma unroll
        for (int mi = 0; mi < 2; ++mi)
            a[mi] = *(const short8*)&As[wm * 32 + mi * 16 + l15][lk * 8];
        #pragma unroll
        for (int ni = 0; ni < 4; ++ni) {
            int nr = wn * 64 + ni * 16 + l15;
            union { uint2 u[2]; short8 v; } bb;
            bb.u[0] = *(const uint2*)&Bs[nr][lk * 4];
            bb.u[1] = *(const uint2*)&Bs[nr][lk * 4 + 2];
            b[ni] = bb.v;
        }
        #pragma unroll
        for (int mi = 0; mi < 2; ++mi)
            #pragma unroll
            for (int ni = 0; ni < 4; ++ni)
                acc[mi][ni] = __builtin_amdgcn_mfma_f32_16x16x32_bf16(a[mi], b[ni], acc[mi][ni], 0, 0, 0);
    }

    #pragma unroll
    for (int mi = 0; mi < 2; ++mi) {
        #pragma unroll
        for (int ni = 0; ni < 4; ++ni) {
            int n = n0 + wn * 64 + ni * 16 + l15;
            #pragma unroll
            for (int r = 0; r < 4; ++r) {
                int node = m0 + wm * 32 + mi * 16 + lk * 4 + r;
                if (n0 < 256) xl[(size_t)node * 256 + n]         = acc[mi][ni][r];
                else          xr[(size_t)node * 256 + (n - 256)] = acc[mi][ni][r];
            }
        }
    }
}

// ---- fused GAT attention v5: permuted LDS layout, vectorized DS traffic ----
__global__ __launch_bounds__(256) void k_attn(const int* __restrict__ ei,
                                              const float* __restrict__ ea,
                                              const float* __restrict__ eeself,
                                              const float* __restrict__ att,
                                              const float* __restrict__ We,
                                              const float* __restrict__ xl,
                                              const float* __restrict__ xr,
                                              const float* __restrict__ bg,
                                              unsigned short* __restrict__ hb) {
    __shared__ float xlS[64][68];    // permuted cols, pitch 68
    __shared__ float xrS[64][68];
    __shared__ float lgS[1088];
    __shared__ int   srcS[1024];

    int t = threadIdx.x;
    int g = blockIdx.x >> 2, h = blockIdx.x & 3;
    int hc0 = h * 64;

    {   // stage xl/xr head slices into PERMUTED layout
        int n = t >> 2, q4 = t & 3;
        const float* xlp = xl + ((size_t)(g * 64 + n)) * 256 + hc0 + q4 * 16;
        const float* xrp = xr + ((size_t)(g * 64 + n)) * 256 + hc0 + q4 * 16;
        #pragma unroll
        for (int i = 0; i < 4; ++i) {
            float4 vl = *(const float4*)(xlp + i * 4);
            float4 vr = *(const float4*)(xrp + i * 4);
            xlS[n][(i * 4 + 0) * 4 + q4] = vl.x;
            xlS[n][(i * 4 + 1) * 4 + q4] = vl.y;
            xlS[n][(i * 4 + 2) * 4 + q4] = vl.z;
            xlS[n][(i * 4 + 3) * 4 + q4] = vl.w;
            xrS[n][(i * 4 + 0) * 4 + q4] = vr.x;
            xrS[n][(i * 4 + 1) * 4 + q4] = vr.y;
            xrS[n][(i * 4 + 2) * 4 + q4] = vr.z;
            xrS[n][(i * 4 + 3) * 4 + q4] = vr.w;
        }
    }
    {   // stage local src indices
        int4 v = *(const int4*)(ei + (size_t)g * 1024 + t * 4);
        srcS[t * 4 + 0] = v.x & 63;
        srcS[t * 4 + 1] = v.y & 63;
        srcS[t * 4 + 2] = v.z & 63;
        srcS[t * 4 + 3] = v.w & 63;
    }

    int wave = t >> 6, lane = t & 63;
    int q = lane >> 4, l15 = lane & 15;

    short8 wf[4];
    float  attv[4];
    #pragma unroll
    for (int nt = 0; nt < 4; ++nt) {
        attv[nt] = att[hc0 + nt * 16 + l15];
        if (q < 2) {
            const float* wp = We + (size_t)(q * 8) * 256 + hc0 + nt * 16 + l15;
            float w0 = wp[0*256], w1 = wp[1*256], w2 = wp[2*256], w3 = wp[3*256];
            float w4 = wp[4*256], w5 = wp[5*256], w6 = wp[6*256], w7 = wp[7*256];
            union { unsigned int u[4]; short8 v; } bb;
            bb.u[0] = packbf2(w0, w1);
            bb.u[1] = packbf2(w2, w3);
            bb.u[2] = packbf2(w4, w5);
            bb.u[3] = packbf2(w6, w7);
            wf[nt] = bb.v;
        } else {
            wf[nt] = (short8)0;
        }
    }
    __syncthreads();

    for (int b = wave; b < 16; b += 4) {
        short8 af[4];
        #pragma unroll
        for (int mt = 0; mt < 4; ++mt) {
            if (q < 2) {
                const float* ep = ea + ((size_t)(g * 1024 + b * 64 + mt * 16 + l15)) * 16 + q * 8;
                float4 v0 = *(const float4*)ep;
                float4 v1 = *(const float4*)(ep + 4);
                union { unsigned int u[4]; short8 v; } bb;
                bb.u[0] = packbf2(v0.x, v0.y);
                bb.u[1] = packbf2(v0.z, v0.w);
                bb.u[2] = packbf2(v1.x, v1.y);
                bb.u[3] = packbf2(v1.z, v1.w);
                af[mt] = bb.v;
            } else {
                af[mt] = (short8)0;
            }
        }
        floatx4 acc[4][4];
        #pragma unroll
        for (int mt = 0; mt < 4; ++mt)
            #pragma unroll
            for (int nt = 0; nt < 4; ++nt)
                acc[mt][nt] = __builtin_amdgcn_mfma_f32_16x16x32_bf16(af[mt], wf[nt], (floatx4)(0.f), 0, 0, 0);

        #pragma unroll
        for (int mt = 0; mt < 4; ++mt) {
            float4 xrv = *(const float4*)&xrS[b * 4 + mt][l15 * 4];
            int4  s4  = *(const int4*)&srcS[b * 64 + mt * 16 + q * 4];
            int sr[4] = {s4.x, s4.y, s4.z, s4.w};
            float lsum[4];
            #pragma unroll
            for (int r = 0; r < 4; ++r) {
                float4 xlv = *(const float4*)&xlS[sr[r]][l15 * 4];
                float f, acc_sum = 0.f;
                f = acc[mt][0][r] + xlv.x + xrv.x; f = fmaxf(f, NEG_SLOPE * f); acc_sum += f * attv[0];
                f = acc[mt][1][r] + xlv.y + xrv.y; f = fmaxf(f, NEG_SLOPE * f); acc_sum += f * attv[1];
                f = acc[mt][2][r] + xlv.z + xrv.z; f = fmaxf(f, NEG_SLOPE * f); acc_sum += f * attv[2];
                f = acc[mt][3][r] + xlv.w + xrv.w; f = fmaxf(f, NEG_SLOPE * f); acc_sum += f * attv[3];
                lsum[r] = acc_sum;
            }
            #pragma unroll
            for (int r = 0; r < 4; ++r) {
                float v = lsum[r];
                v = dpp_add<0x111>(v);
                v = dpp_add<0x112>(v);
                v = dpp_add<0x114>(v);
                v = dpp_add<0x118>(v);
                if (l15 == 15) lgS[b * 64 + mt * 16 + q * 4 + r] = v;
            }
        }
    }

    {   // self-loop batch (permuted indexing)
        int n = wave * 16 + l15;
        float sum = 0.f;
        const float* eep = eeself + hc0 + q * 16;
        const float* ap  = att + hc0 + q * 16;
        #pragma unroll
        for (int i = 0; i < 4; ++i) {
            float4 ev = *(const float4*)(eep + i * 4);
            float4 av = *(const float4*)(ap + i * 4);
            #pragma unroll
            for (int j = 0; j < 4; ++j) {
                int p = (i * 4 + j) * 4 + q;
                float e = (j == 0) ? ev.x : (j == 1) ? ev.y : (j == 2) ? ev.z : ev.w;
                float a = (j == 0) ? av.x : (j == 1) ? av.y : (j == 2) ? av.z : av.w;
                float f = xlS[n][p] + xrS[n][p] + e;
                f = fmaxf(f, NEG_SLOPE * f);
                sum += f * a;
            }
        }
        sum += __shfl_xor(sum, 16);
        sum += __shfl_xor(sum, 32);
        if (q == 0) lgS[1024 + n] = sum;
    }
    __syncthreads();

    if (t < 64) {
        float lg[17];
        #pragma unroll
        for (int j = 0; j < 16; ++j) lg[j] = lgS[t * 16 + j];
        lg[16] = lgS[1024 + t];
        float m = lg[0];
        #pragma unroll
        for (int j = 1; j < 17; ++j) m = fmaxf(m, lg[j]);
        float ex[17], ssum = 0.f;
        #pragma unroll
        for (int j = 0; j < 17; ++j) { ex[j] = __expf(lg[j] - m); ssum += ex[j]; }
        float inv = 1.f / (17.f * ssum);
        #pragma unroll
        for (int j = 0; j < 16; ++j) lgS[t * 16 + j] = ex[j] * inv;
        lgS[1024 + t] = ex[16] * inv;
    }
    __syncthreads();

    {   // aggregation: lane = logical col c; permuted read position pc
        int c = lane;
        int pc = (c & 15) * 4 + (c >> 4);
        float bgv = bg[hc0 + c];
        for (int n = wave * 16; n < wave * 16 + 16; ++n) {
            float4 al0 = *(const float4*)&lgS[n * 16];
            float4 al1 = *(const float4*)&lgS[n * 16 + 4];
            float4 al2 = *(const float4*)&lgS[n * 16 + 8];
            float4 al3 = *(const float4*)&lgS[n * 16 + 12];
            int4  s0  = *(const int4*)&srcS[n * 16];
            int4  s1  = *(const int4*)&srcS[n * 16 + 4];
            int4  s2  = *(const int4*)&srcS[n * 16 + 8];
            int4  s3  = *(const int4*)&srcS[n * 16 + 12];
            float a0 = lgS[1024 + n] * xlS[n][pc];
            float a1 = 0.f;
            a0 += al0.x * xlS[s0.x][pc];  a1 += al0.y * xlS[s0.y][pc];
            a0 += al0.z * xlS[s0.z][pc];  a1 += al0.w * xlS[s0.w][pc];
            a0 += al1.x * xlS[s1.x][pc];  a1 += al1.y * xlS[s1.y][pc];
            a0 += al1.z * xlS[s1.z][pc];  a1 += al1.w * xlS[s1.w][pc];
            a0 += al2.x * xlS[s2.x][pc];  a1 += al2.y * xlS[s2.y][pc];
            a0 += al2.z * xlS[s2.z][pc];  a1 += al2.w * xlS[s2.w][pc];
            a0 += al3.x * xlS[s3.x][pc];  a1 += al3.y * xlS[s3.y][pc];
            a0 += al3.z * xlS[s3.z][pc];  a1 += al3.w * xlS[s3.w][pc];
            float val = a0 + a1 + bgv;
            hb[((size_t)(g * 64 + n)) * 256 + hc0 + c] = f2bf(val);
        }
    }
}

// ---- big GEMM v7: 1-iter-deep prefetch, counted vmcnt, unroll-2 ------------
__global__ __launch_bounds__(256) void k_gemm(const unsigned short* __restrict__ hb,
                                              const float* __restrict__ W,
                                              float* __restrict__ parts) {
    __shared__ unsigned short As[2][256 * 32];
    __shared__ unsigned int   Bs[2][64][18];

    int t = threadIdx.x;
    int wave = t >> 6, lane = t & 63;
    int l15 = lane & 15, lk = lane >> 4;
    int n0 = blockIdx.x * 64;
    int s  = blockIdx.y;
    int kbase = s * 2048;

    floatx4 acc[4][4];
    #pragma unroll
    for (int i = 0; i < 4; ++i)
        #pragma unroll
        for (int j = 0; j < 4; ++j)
            acc[i][j] = (floatx4)(0.f);

    int gc = ((lane & 3) - ((lane >> 3) & 3)) & 3;
    const unsigned short* a_src =
        hb + (size_t)(wave * 64 + (lane >> 2)) * KDIM + kbase + gc * 8;
    int ap_off[4];
    #pragma unroll
    for (int mi = 0; mi < 4; ++mi)
        ap_off[mi] = (wave * 64 + mi * 16 + l15) * 32 + (((lk + (l15 >> 1)) & 3) * 8);

    int bkp = t >> 4;
    int bc8 = t & 15;
    const float* b_src = W + (size_t)(kbase + 2 * bkp) * 4096 + n0 + bc8 * 4;

    #define ISSUE_A(step, buf)                                                   \
        {                                                                        \
            const unsigned short* gp_ = a_src + (size_t)(step) * 32;             \
            _Pragma("unroll")                                                    \
            for (int i_ = 0; i_ < 4; ++i_) {                                     \
                __builtin_amdgcn_global_load_lds(                                \
                    (const __attribute__((address_space(1))) unsigned int*)      \
                        (gp_ + (size_t)i_ * 16 * KDIM),                          \
                    (__attribute__((address_space(3))) unsigned int*)            \
                        &As[buf][(wave * 64 + i_ * 16) * 32],                    \
                    16, 0, 0);                                                   \
            }                                                                    \
        }
    #define LOAD_B(step, r0, r1)                                                 \
        {                                                                        \
            const float* wp_ = b_src + (size_t)(step) * 32 * 4096;               \
            r0 = *(const float4*)wp_;                                            \
            r1 = *(const float4*)(wp_ + 4096);                                   \
        }
    #define WRITE_B(buf, r0, r1)                                                 \
        {                                                                        \
            Bs[buf][bc8 * 4 + 0][bkp] = packbf2(r0.x, r1.x);                     \
            Bs[buf][bc8 * 4 + 1][bkp] = packbf2(r0.y, r1.y);                     \
            Bs[buf][bc8 * 4 + 2][bkp] = packbf2(r0.z, r1.z);                     \
            Bs[buf][bc8 * 4 + 3][bkp] = packbf2(r0.w, r1.w);                     \
        }
    #define COMPUTE(abuf, bbuf)                                                  \
        {                                                                        \
            short8 a_[4], b_[4];                                                 \
            _Pragma("unroll")                                                    \
            for (int mi = 0; mi < 4; ++mi)                                       \
                a_[mi] = *(const short8*)&As[abuf][ap_off[mi]];                  \
            _Pragma("unroll")                                                    \
            for (int ni = 0; ni < 4; ++ni) {                                     \
                int nr_ = ni * 16 + l15;                                         \
                union { uint2 u[2]; short8 v; } bb_;                             \
                bb_.u[0] = *(const uint2*)&Bs[bbuf][nr_][lk * 4];                \
                bb_.u[1] = *(const uint2*)&Bs[bbuf][nr_][lk * 4 + 2];            \
                b_[ni] = bb_.v;                                                  \
            }                                                                    \
            __builtin_amdgcn_s_setprio(1);                                       \
            _Pragma("unroll")                                                    \
            for (int mi = 0; mi < 4; ++mi)                                       \
                _Pragma("unroll")                                                \
                for (int ni = 0; ni < 4; ++ni)                                   \
                    acc[mi][ni] = __builtin_amdgcn_mfma_f32_16x16x32_bf16(       \
                        a_[mi], b_[ni], acc[mi][ni], 0, 0, 0);                   \
            __builtin_amdgcn_s_setprio(0);                                       \
        }
    #define VMCNT(n) __builtin_amdgcn_sched_barrier(0);                          \
                     asm volatile("s_waitcnt vmcnt(" #n ")" ::: "memory");       \
                     __builtin_amdgcn_sched_barrier(0)
    #define LGKM0    asm volatile("s_waitcnt lgkmcnt(0)" ::: "memory");          \
                     __builtin_amdgcn_sched_barrier(0)

    float4 e0, e1, o0, o1;

    ISSUE_A(0, 0);
    LOAD_B(0, e0, e1);
    LOAD_B(1, o0, o1);
    VMCNT(2);
    WRITE_B(0, e0, e1);
    LGKM0;
    __builtin_amdgcn_s_barrier();

    for (int j = 0; j < 62; j += 2) {
        ISSUE_A(j + 1, 1);
        LOAD_B(j + 2, e0, e1);
        VMCNT(8);
        COMPUTE(0, 0);
        VMCNT(6);
        WRITE_B(1, o0, o1);
        LGKM0;
        __builtin_amdgcn_s_barrier();
        ISSUE_A(j + 2, 0);
        LOAD_B(j + 3, o0, o1);
        VMCNT(8);
        COMPUTE(1, 1);
        VMCNT(6);
        WRITE_B(0, e0, e1);
        LGKM0;
        __builtin_amdgcn_s_barrier();
    }
    {
        ISSUE_A(63, 1);
        VMCNT(6);
        COMPUTE(0, 0);
        VMCNT(4);
        WRITE_B(1, o0, o1);
        LGKM0;
        __builtin_amdgcn_s_barrier();
    }
    VMCNT(0);
    COMPUTE(1, 1);

    #undef ISSUE_A
    #undef LOAD_B
    #undef WRITE_B
    #undef COMPUTE
    #undef VMCNT
    #undef LGKM0

    float* dst = parts + (size_t)s * (256 * 4096);
    #pragma unroll
    for (int mi = 0; mi < 4; ++mi) {
        #pragma unroll
        for (int ni = 0; ni < 4; ++ni) {
            int col = n0 + ni * 16 + l15;
            #pragma unroll
            for (int r = 0; r < 4; ++r) {
                int row = wave * 64 + mi * 16 + lk * 4 + r;
                dst[(size_t)row * 4096 + col] = acc[mi][ni][r];
            }
        }
    }
}

// ---- reduce partials + bias -> d_out ---------------------------------------
__global__ __launch_bounds__(256) void k_reduce(const float* __restrict__ parts,
                                                const float* __restrict__ linb,
                                                float* __restrict__ out) {
    int idx = blockIdx.x * 256 + threadIdx.x;
    float v = linb[idx & 4095];
    #pragma unroll
    for (int s = 0; s < 8; ++s) v += parts[(size_t)s * (256 * 4096) + idx];
    out[idx] = v;
}

extern "C" void kernel_launch(void* const* d_in, const int* in_sizes, int n_in,
                              void* d_out, int out_size, void* d_ws, size_t ws_size,
                              hipStream_t stream) {
    (void)in_sizes; (void)n_in; (void)out_size; (void)ws_size;
    const float* x   = (const float*)d_in[0];
    const int*   ei  = (const int*)d_in[1];
    const float* ea  = (const float*)d_in[2];
    /* d_in[3] = batch (unused, fixed layout) */
    const float* Wl  = (const float*)d_in[4];
    const float* Wr  = (const float*)d_in[5];
    const float* We  = (const float*)d_in[6];
    const float* att = (const float*)d_in[7];
    const float* bg  = (const float*)d_in[8];
    const float* W   = (const float*)d_in[9];
    const float* lb  = (const float*)d_in[10];
    float* out = (float*)d_out;

    char* p = (char*)d_ws;
    float* xl           = (float*)p;          p += 16777216;           // 16384x256 f32
    float* xr           = (float*)p;          p += 16777216;
    unsigned short* hb  = (unsigned short*)p; p += 8388608;            // 16384x256 bf16
    float* parts        = (float*)p;          p += 33554432;           // 8x256x4096 f32
    unsigned short* hb2 = (unsigned short*)p; p += 33554432;           // MEASUREMENT scratch
    float* eapart       = (float*)p;          p += 16384;              // 256x16
    float* eeself       = (float*)p;          p += 1024;               // 256

    k_ea_part  <<<256,  256, 0, stream>>>(ea, eapart);
    k_ea_finish<<<1,    256, 0, stream>>>(eapart, We, eeself);
    k_xlr2     <<<dim3(256, 4), 256, 0, stream>>>(x, Wl, Wr, xl, xr);
    // MEASUREMENT: duplicate attn into scratch; Delta(total) vs R7 = attn cost.
    k_attn     <<<1024, 256, 0, stream>>>(ei, ea, eeself, att, We, xl, xr, bg, hb2);
    k_attn     <<<1024, 256, 0, stream>>>(ei, ea, eeself, att, We, xl, xr, bg, hb);
    k_gemm     <<<dim3(64, 8), 256, 0, stream>>>(hb, W, parts);
    k_reduce   <<<4096, 256, 0, stream>>>(parts, lb, out);
}

// Round 10
// 185.636 us; speedup vs baseline: 1.4779x; 1.2389x over previous
//
#include <hip/hip_runtime.h>
#include <hip/hip_bf16.h>

// Problem constants (fixed by reference)
#define N_NODES   16384
#define DEG       16
#define EDGES     262144          // N_NODES*DEG
#define HC        256             // HEADS*OUT_C
#define KDIM      16384           // 64 nodes * 256 feat
#define NEG_SLOPE 0.2f

typedef __attribute__((ext_vector_type(8))) short short8;   // 8 bf16
typedef __attribute__((ext_vector_type(4))) float floatx4;

static __device__ __forceinline__ unsigned short f2bf(float f) {
    union { __hip_bfloat16 h; unsigned short u; } c;
    c.h = __float2bfloat16(f);          // RNE
    return c.u;
}
static __device__ __forceinline__ unsigned int packbf2(float lo, float hi) {
    union { __hip_bfloat162 h2; unsigned int u; } c;
    c.h2 = __float22bfloat162_rn(make_float2(lo, hi));   // v_cvt_pk_bf16_f32
    return c.u;
}

// DPP row_shr add chain {1,2,4,8}: lane l15==15 holds the 16-lane sum.
template <int CTRL>
static __device__ __forceinline__ float dpp_add(float v) {
    int x = __builtin_amdgcn_update_dpp(0, __float_as_int(v), CTRL, 0xF, 0xF, true);
    return v + __int_as_float(x);
}

// ---- mean(edge_attr) partial sums: 256 blocks x 1024 rows -----------------
__global__ __launch_bounds__(256) void k_ea_part(const float* __restrict__ ea,
                                                 float* __restrict__ part) {
    __shared__ float s[256];
    int b = blockIdx.x, t = threadIdx.x;
    int col = t & 15, r0 = t >> 4;
    const float* base = ea + (size_t)b * 1024 * 16;
    float acc = 0.f;
    for (int r = r0; r < 1024; r += 16) acc += base[r * 16 + col];
    s[t] = acc; __syncthreads();
    for (int off = 128; off >= 16; off >>= 1) {
        if (t < off) s[t] += s[t + off];
        __syncthreads();
    }
    if (t < 16) part[b * 16 + t] = s[t];
}

// ---- finish mean + ee_self = mean_ea @ W_e (parallel, 2-level tree) --------
__global__ __launch_bounds__(256) void k_ea_finish(const float* __restrict__ part,
                                                   const float* __restrict__ We,
                                                   float* __restrict__ eeself) {
    __shared__ float ps[16][16];
    __shared__ float mean[16];
    int t = threadIdx.x;
    int col = t & 15, bg = t >> 4;
    float a = 0.f;
    #pragma unroll
    for (int i = 0; i < 16; ++i)
        a += part[(bg + i * 16) * 16 + col];
    ps[bg][col] = a;
    __syncthreads();
    if (t < 16) {
        float m = 0.f;
        #pragma unroll
        for (int i = 0; i < 16; ++i) m += ps[i][t];
        mean[t] = m * (1.f / (float)EDGES);
    }
    __syncthreads();
    float acc = 0.f;
    #pragma unroll
    for (int d = 0; d < 16; ++d) acc += mean[d] * We[d * 256 + t];
    eeself[t] = acc;
}

// ---- xl|xr via MFMA: (16384 x 128) @ (128 x 512) ---------------------------
__global__ __launch_bounds__(256) void k_xlr2(const float* __restrict__ x,
                                              const float* __restrict__ Wl,
                                              const float* __restrict__ Wr,
                                              float* __restrict__ xl,
                                              float* __restrict__ xr) {
    __shared__ unsigned short As[64][40];   // [row][k] bf16
    __shared__ unsigned int   Bs[128][18];  // [col][kpair]
    unsigned int* As32 = (unsigned int*)&As[0][0];

    int t = threadIdx.x;
    int wave = t >> 6, lane = t & 63;
    int l15 = lane & 15, lk = lane >> 4;
    int wm = wave >> 1, wn = wave & 1;
    int m0 = blockIdx.x * 64;
    int n0 = blockIdx.y * 128;
    const float* Wsel = (n0 < 256) ? Wl : Wr;
    int bc = n0 & 255;

    floatx4 acc[2][4];
    #pragma unroll
    for (int i = 0; i < 2; ++i)
        #pragma unroll
        for (int j = 0; j < 4; ++j)
            acc[i][j] = (floatx4)(0.f);

    int ar = t >> 2, ac = t & 3;
    int bkp = t >> 4, bcc = t & 15;

    for (int k0 = 0; k0 < 128; k0 += 32) {
        __syncthreads();
        {   // stage A: x[m0+r][k0 + ac*8 .. +7] -> bf16
            const float* gp = x + (size_t)(m0 + ar) * 128 + k0 + ac * 8;
            float4 v0 = *(const float4*)gp;
            float4 v1 = *(const float4*)(gp + 4);
            As32[ar * 20 + ac * 4 + 0] = packbf2(v0.x, v0.y);
            As32[ar * 20 + ac * 4 + 1] = packbf2(v0.z, v0.w);
            As32[ar * 20 + ac * 4 + 2] = packbf2(v1.x, v1.y);
            As32[ar * 20 + ac * 4 + 3] = packbf2(v1.z, v1.w);
        }
        {   // stage B
            const float* wp = Wsel + (size_t)(k0 + 2 * bkp) * 256 + bc + bcc * 8;
            float4 r0a = *(const float4*)wp;
            float4 r0b = *(const float4*)(wp + 4);
            float4 r1a = *(const float4*)(wp + 256);
            float4 r1b = *(const float4*)(wp + 260);
            Bs[bcc * 8 + 0][bkp] = packbf2(r0a.x, r1a.x);
            Bs[bcc * 8 + 1][bkp] = packbf2(r0a.y, r1a.y);
            Bs[bcc * 8 + 2][bkp] = packbf2(r0a.z, r1a.z);
            Bs[bcc * 8 + 3][bkp] = packbf2(r0a.w, r1a.w);
            Bs[bcc * 8 + 4][bkp] = packbf2(r0b.x, r1b.x);
            Bs[bcc * 8 + 5][bkp] = packbf2(r0b.y, r1b.y);
            Bs[bcc * 8 + 6][bkp] = packbf2(r0b.z, r1b.z);
            Bs[bcc * 8 + 7][bkp] = packbf2(r0b.w, r1b.w);
        }
        __syncthreads();
        short8 a[2], b[4];
        #pragma unroll
        for (int mi = 0; mi < 2; ++mi)
            a[mi] = *(const short8*)&As[wm * 32 + mi * 16 + l15][lk * 8];
        #pragma unroll
        for (int ni = 0; ni < 4; ++ni) {
            int nr = wn * 64 + ni * 16 + l15;
            union { uint2 u[2]; short8 v; } bb;
            bb.u[0] = *(const uint2*)&Bs[nr][lk * 4];
            bb.u[1] = *(const uint2*)&Bs[nr][lk * 4 + 2];
            b[ni] = bb.v;
        }
        #pragma unroll
        for (int mi = 0; mi < 2; ++mi)
            #pragma unroll
            for (int ni = 0; ni < 4; ++ni)
                acc[mi][ni] = __builtin_amdgcn_mfma_f32_16x16x32_bf16(a[mi], b[ni], acc[mi][ni], 0, 0, 0);
    }

    #pragma unroll
    for (int mi = 0; mi < 2; ++mi) {
        #pragma unroll
        for (int ni = 0; ni < 4; ++ni) {
            int n = n0 + wn * 64 + ni * 16 + l15;
            #pragma unroll
            for (int r = 0; r < 4; ++r) {
                int node = m0 + wm * 32 + mi * 16 + lk * 4 + r;
                if (n0 < 256) xl[(size_t)node * 256 + n]         = acc[mi][ni][r];
                else          xr[(size_t)node * 256 + (n - 256)] = acc[mi][ni][r];
            }
        }
    }
}

// ---- fused GAT attention v6: LDS < 40KB (uchar src) -> 4 blocks/CU ---------
// Arithmetic is bit-identical to v5 (absmax canary 0.0078125 must hold).
__global__ __launch_bounds__(256) void k_attn(const int* __restrict__ ei,
                                              const float* __restrict__ ea,
                                              const float* __restrict__ eeself,
                                              const float* __restrict__ att,
                                              const float* __restrict__ We,
                                              const float* __restrict__ xl,
                                              const float* __restrict__ xr,
                                              const float* __restrict__ bg,
                                              unsigned short* __restrict__ hb) {
    __shared__ float xlS[64][68];    // permuted cols, pitch 68
    __shared__ float xrS[64][68];
    __shared__ float lgS[1088];
    __shared__ unsigned char srcS[1024];   // local src (0..63) fits a byte

    int t = threadIdx.x;
    int g = blockIdx.x >> 2, h = blockIdx.x & 3;
    int hc0 = h * 64;
    unsigned int* srcSu = (unsigned int*)srcS;

    {   // stage xl/xr head slices into PERMUTED layout
        int n = t >> 2, q4 = t & 3;
        const float* xlp = xl + ((size_t)(g * 64 + n)) * 256 + hc0 + q4 * 16;
        const float* xrp = xr + ((size_t)(g * 64 + n)) * 256 + hc0 + q4 * 16;
        #pragma unroll
        for (int i = 0; i < 4; ++i) {
            float4 vl = *(const float4*)(xlp + i * 4);
            float4 vr = *(const float4*)(xrp + i * 4);
            xlS[n][(i * 4 + 0) * 4 + q4] = vl.x;
            xlS[n][(i * 4 + 1) * 4 + q4] = vl.y;
            xlS[n][(i * 4 + 2) * 4 + q4] = vl.z;
            xlS[n][(i * 4 + 3) * 4 + q4] = vl.w;
            xrS[n][(i * 4 + 0) * 4 + q4] = vr.x;
            xrS[n][(i * 4 + 1) * 4 + q4] = vr.y;
            xrS[n][(i * 4 + 2) * 4 + q4] = vr.z;
            xrS[n][(i * 4 + 3) * 4 + q4] = vr.w;
        }
    }
    {   // stage local src indices, packed 4/uint
        int4 v = *(const int4*)(ei + (size_t)g * 1024 + t * 4);
        srcSu[t] = (unsigned int)(v.x & 63) | ((unsigned int)(v.y & 63) << 8) |
                   ((unsigned int)(v.z & 63) << 16) | ((unsigned int)(v.w & 63) << 24);
    }

    int wave = t >> 6, lane = t & 63;
    int q = lane >> 4, l15 = lane & 15;

    short8 wf[4];
    float  attv[4];
    #pragma unroll
    for (int nt = 0; nt < 4; ++nt) {
        attv[nt] = att[hc0 + nt * 16 + l15];
        if (q < 2) {
            const float* wp = We + (size_t)(q * 8) * 256 + hc0 + nt * 16 + l15;
            float w0 = wp[0*256], w1 = wp[1*256], w2 = wp[2*256], w3 = wp[3*256];
            float w4 = wp[4*256], w5 = wp[5*256], w6 = wp[6*256], w7 = wp[7*256];
            union { unsigned int u[4]; short8 v; } bb;
            bb.u[0] = packbf2(w0, w1);
            bb.u[1] = packbf2(w2, w3);
            bb.u[2] = packbf2(w4, w5);
            bb.u[3] = packbf2(w6, w7);
            wf[nt] = bb.v;
        } else {
            wf[nt] = (short8)0;
        }
    }
    __syncthreads();

    for (int b = wave; b < 16; b += 4) {
        short8 af[4];
        #pragma unroll
        for (int mt = 0; mt < 4; ++mt) {
            if (q < 2) {
                const float* ep = ea + ((size_t)(g * 1024 + b * 64 + mt * 16 + l15)) * 16 + q * 8;
                float4 v0 = *(const float4*)ep;
                float4 v1 = *(const float4*)(ep + 4);
                union { unsigned int u[4]; short8 v; } bb;
                bb.u[0] = packbf2(v0.x, v0.y);
                bb.u[1] = packbf2(v0.z, v0.w);
                bb.u[2] = packbf2(v1.x, v1.y);
                bb.u[3] = packbf2(v1.z, v1.w);
                af[mt] = bb.v;
            } else {
                af[mt] = (short8)0;
            }
        }
        floatx4 acc[4][4];
        #pragma unroll
        for (int mt = 0; mt < 4; ++mt)
            #pragma unroll
            for (int nt = 0; nt < 4; ++nt)
                acc[mt][nt] = __builtin_amdgcn_mfma_f32_16x16x32_bf16(af[mt], wf[nt], (floatx4)(0.f), 0, 0, 0);

        #pragma unroll
        for (int mt = 0; mt < 4; ++mt) {
            float4 xrv = *(const float4*)&xrS[b * 4 + mt][l15 * 4];
            unsigned int sw = srcSu[b * 16 + mt * 4 + q];
            int sr[4] = {(int)(sw & 255), (int)((sw >> 8) & 255),
                         (int)((sw >> 16) & 255), (int)(sw >> 24)};
            float lsum[4];
            #pragma unroll
            for (int r = 0; r < 4; ++r) {
                float4 xlv = *(const float4*)&xlS[sr[r]][l15 * 4];
                float f, acc_sum = 0.f;
                f = acc[mt][0][r] + xlv.x + xrv.x; f = fmaxf(f, NEG_SLOPE * f); acc_sum += f * attv[0];
                f = acc[mt][1][r] + xlv.y + xrv.y; f = fmaxf(f, NEG_SLOPE * f); acc_sum += f * attv[1];
                f = acc[mt][2][r] + xlv.z + xrv.z; f = fmaxf(f, NEG_SLOPE * f); acc_sum += f * attv[2];
                f = acc[mt][3][r] + xlv.w + xrv.w; f = fmaxf(f, NEG_SLOPE * f); acc_sum += f * attv[3];
                lsum[r] = acc_sum;
            }
            #pragma unroll
            for (int r = 0; r < 4; ++r) {
                float v = lsum[r];
                v = dpp_add<0x111>(v);
                v = dpp_add<0x112>(v);
                v = dpp_add<0x114>(v);
                v = dpp_add<0x118>(v);
                if (l15 == 15) lgS[b * 64 + mt * 16 + q * 4 + r] = v;
            }
        }
    }

    {   // self-loop batch (permuted indexing)
        int n = wave * 16 + l15;
        float sum = 0.f;
        const float* eep = eeself + hc0 + q * 16;
        const float* ap  = att + hc0 + q * 16;
        #pragma unroll
        for (int i = 0; i < 4; ++i) {
            float4 ev = *(const float4*)(eep + i * 4);
            float4 av = *(const float4*)(ap + i * 4);
            #pragma unroll
            for (int j = 0; j < 4; ++j) {
                int p = (i * 4 + j) * 4 + q;
                float e = (j == 0) ? ev.x : (j == 1) ? ev.y : (j == 2) ? ev.z : ev.w;
                float a = (j == 0) ? av.x : (j == 1) ? av.y : (j == 2) ? av.z : av.w;
                float f = xlS[n][p] + xrS[n][p] + e;
                f = fmaxf(f, NEG_SLOPE * f);
                sum += f * a;
            }
        }
        sum += __shfl_xor(sum, 16);
        sum += __shfl_xor(sum, 32);
        if (q == 0) lgS[1024 + n] = sum;
    }
    __syncthreads();

    if (t < 64) {
        float lg[17];
        #pragma unroll
        for (int j = 0; j < 16; ++j) lg[j] = lgS[t * 16 + j];
        lg[16] = lgS[1024 + t];
        float m = lg[0];
        #pragma unroll
        for (int j = 1; j < 17; ++j) m = fmaxf(m, lg[j]);
        float ex[17], ssum = 0.f;
        #pragma unroll
        for (int j = 0; j < 17; ++j) { ex[j] = __expf(lg[j] - m); ssum += ex[j]; }
        float inv = 1.f / (17.f * ssum);
        #pragma unroll
        for (int j = 0; j < 16; ++j) lgS[t * 16 + j] = ex[j] * inv;
        lgS[1024 + t] = ex[16] * inv;
    }
    __syncthreads();

    {   // aggregation: lane = logical col c; permuted read position pc
        int c = lane;
        int pc = (c & 15) * 4 + (c >> 4);
        float bgv = bg[hc0 + c];
        for (int n = wave * 16; n < wave * 16 + 16; ++n) {
            float4 al0 = *(const float4*)&lgS[n * 16];
            float4 al1 = *(const float4*)&lgS[n * 16 + 4];
            float4 al2 = *(const float4*)&lgS[n * 16 + 8];
            float4 al3 = *(const float4*)&lgS[n * 16 + 12];
            unsigned int w0 = srcSu[n * 4 + 0], w1 = srcSu[n * 4 + 1];
            unsigned int w2 = srcSu[n * 4 + 2], w3 = srcSu[n * 4 + 3];
            float a0 = lgS[1024 + n] * xlS[n][pc];
            float a1 = 0.f;
            a0 += al0.x * xlS[w0 & 255][pc];        a1 += al0.y * xlS[(w0 >> 8) & 255][pc];
            a0 += al0.z * xlS[(w0 >> 16) & 255][pc]; a1 += al0.w * xlS[w0 >> 24][pc];
            a0 += al1.x * xlS[w1 & 255][pc];        a1 += al1.y * xlS[(w1 >> 8) & 255][pc];
            a0 += al1.z * xlS[(w1 >> 16) & 255][pc]; a1 += al1.w * xlS[w1 >> 24][pc];
            a0 += al2.x * xlS[w2 & 255][pc];        a1 += al2.y * xlS[(w2 >> 8) & 255][pc];
            a0 += al2.z * xlS[(w2 >> 16) & 255][pc]; a1 += al2.w * xlS[w2 >> 24][pc];
            a0 += al3.x * xlS[w3 & 255][pc];        a1 += al3.y * xlS[(w3 >> 8) & 255][pc];
            a0 += al3.z * xlS[(w3 >> 16) & 255][pc]; a1 += al3.w * xlS[w3 >> 24][pc];
            float val = a0 + a1 + bgv;
            hb[((size_t)(g * 64 + n)) * 256 + hc0 + c] = f2bf(val);
        }
    }
}

// ---- big GEMM v8: A 2-ahead (As[3]), B 3-ahead (3 reg sets), unroll-6 ------
// Ledger/iter j: entry [B(j+1):2, A(j+1):4, B(j+2):2]=8; ISSUE_A(j+2) +4,
// LOAD_B(j+3) +2 -> 14; COMPUTE (A(j),Bs[j&1] ready from prior iter);
// VMCNT(8) completes B(j+1)+A(j+1); WRITE_B(Bs[(j+1)&1], set[(j+1)%3]);
// barrier. Exit = entry(j+1). B gets ~2.2 iters of latency hiding.
__global__ __launch_bounds__(256) void k_gemm(const unsigned short* __restrict__ hb,
                                              const float* __restrict__ W,
                                              float* __restrict__ parts) {
    __shared__ unsigned short As[3][256 * 32];
    __shared__ unsigned int   Bs[2][64][18];

    int t = threadIdx.x;
    int wave = t >> 6, lane = t & 63;
    int l15 = lane & 15, lk = lane >> 4;
    int n0 = blockIdx.x * 64;
    int s  = blockIdx.y;
    int kbase = s * 2048;

    floatx4 acc[4][4];
    #pragma unroll
    for (int i = 0; i < 4; ++i)
        #pragma unroll
        for (int j = 0; j < 4; ++j)
            acc[i][j] = (floatx4)(0.f);

    int gc = ((lane & 3) - ((lane >> 3) & 3)) & 3;
    const unsigned short* a_src =
        hb + (size_t)(wave * 64 + (lane >> 2)) * KDIM + kbase + gc * 8;
    int ap_off[4];
    #pragma unroll
    for (int mi = 0; mi < 4; ++mi)
        ap_off[mi] = (wave * 64 + mi * 16 + l15) * 32 + (((lk + (l15 >> 1)) & 3) * 8);

    int bkp = t >> 4;
    int bc8 = t & 15;
    const float* b_src = W + (size_t)(kbase + 2 * bkp) * 4096 + n0 + bc8 * 4;

    #define ISSUE_A(step, buf)                                                   \
        {                                                                        \
            const unsigned short* gp_ = a_src + (size_t)(step) * 32;             \
            _Pragma("unroll")                                                    \
            for (int i_ = 0; i_ < 4; ++i_) {                                     \
                __builtin_amdgcn_global_load_lds(                                \
                    (const __attribute__((address_space(1))) unsigned int*)      \
                        (gp_ + (size_t)i_ * 16 * KDIM),                          \
                    (__attribute__((address_space(3))) unsigned int*)            \
                        &As[buf][(wave * 64 + i_ * 16) * 32],                    \
                    16, 0, 0);                                                   \
            }                                                                    \
        }
    #define LOAD_B(step, r0, r1)                                                 \
        {                                                                        \
            const float* wp_ = b_src + (size_t)(step) * 32 * 4096;               \
            r0 = *(const float4*)wp_;                                            \
            r1 = *(const float4*)(wp_ + 4096);                                   \
        }
    #define WRITE_B(buf, r0, r1)                                                 \
        {                                                                        \
            Bs[buf][bc8 * 4 + 0][bkp] = packbf2(r0.x, r1.x);                     \
            Bs[buf][bc8 * 4 + 1][bkp] = packbf2(r0.y, r1.y);                     \
            Bs[buf][bc8 * 4 + 2][bkp] = packbf2(r0.z, r1.z);                     \
            Bs[buf][bc8 * 4 + 3][bkp] = packbf2(r0.w, r1.w);                     \
        }
    #define COMPUTE(abuf, bbuf)                                                  \
        {                                                                        \
            short8 a_[4], b_[4];                                                 \
            _Pragma("unroll")                                                    \
            for (int mi = 0; mi < 4; ++mi)                                       \
                a_[mi] = *(const short8*)&As[abuf][ap_off[mi]];                  \
            _Pragma("unroll")                                                    \
            for (int ni = 0; ni < 4; ++ni) {                                     \
                int nr_ = ni * 16 + l15;                                         \
                union { uint2 u[2]; short8 v; } bb_;                             \
                bb_.u[0] = *(const uint2*)&Bs[bbuf][nr_][lk * 4];                \
                bb_.u[1] = *(const uint2*)&Bs[bbuf][nr_][lk * 4 + 2];            \
                b_[ni] = bb_.v;                                                  \
            }                                                                    \
            __builtin_amdgcn_s_setprio(1);                                       \
            _Pragma("unroll")                                                    \
            for (int mi = 0; mi < 4; ++mi)                                       \
                _Pragma("unroll")                                                \
                for (int ni = 0; ni < 4; ++ni)                                   \
                    acc[mi][ni] = __builtin_amdgcn_mfma_f32_16x16x32_bf16(       \
                        a_[mi], b_[ni], acc[mi][ni], 0, 0, 0);                   \
            __builtin_amdgcn_s_setprio(0);                                       \
        }
    #define VMCNT(n) __builtin_amdgcn_sched_barrier(0);                          \
                     asm volatile("s_waitcnt vmcnt(" #n ")" ::: "memory");       \
                     __builtin_amdgcn_sched_barrier(0)
    #define LGKM0    asm volatile("s_waitcnt lgkmcnt(0)" ::: "memory");          \
                     __builtin_amdgcn_sched_barrier(0)
    #define STEP(jA, abufI, jB, ldS0, ldS1, cA, cB, wB, wS0, wS1, VM)            \
        ISSUE_A(jA, abufI);                                                      \
        LOAD_B(jB, ldS0, ldS1);                                                  \
        COMPUTE(cA, cB);                                                         \
        VMCNT(VM);                                                               \
        WRITE_B(wB, wS0, wS1);                                                   \
        LGKM0;                                                                   \
        __builtin_amdgcn_s_barrier();

    float4 s0a, s0b, s1a, s1b, s2a, s2b;   // B reg sets 0,1,2 (set = step%3)

    // ---- prologue: A(0),B(0),A(1),B(1),B(2) in flight; write Bs[0] ----
    ISSUE_A(0, 0);
    LOAD_B(0, s0a, s0b);
    ISSUE_A(1, 1);
    LOAD_B(1, s1a, s1b);
    LOAD_B(2, s2a, s2b);
    VMCNT(8);                 // A(0)+B(0) done
    WRITE_B(0, s0a, s0b);
    LGKM0;
    __builtin_amdgcn_s_barrier();

    // ---- steady: iters 0..59, unrolled by 6 (all mod-2/mod-3 static) ----
    for (int j = 0; j < 60; j += 6) {
        STEP(j + 2, 2, j + 3, s0a, s0b, 0, 0, 1, s1a, s1b, 8)   // iter j+0
        STEP(j + 3, 0, j + 4, s1a, s1b, 1, 1, 0, s2a, s2b, 8)   // iter j+1
        STEP(j + 4, 1, j + 5, s2a, s2b, 2, 0, 1, s0a, s0b, 8)   // iter j+2
        STEP(j + 5, 2, j + 6, s0a, s0b, 0, 1, 0, s1a, s1b, 8)   // iter j+3
        STEP(j + 6, 0, j + 7, s1a, s1b, 1, 0, 1, s2a, s2b, 8)   // iter j+4
        STEP(j + 7, 1, j + 8, s2a, s2b, 2, 1, 0, s0a, s0b, 8)   // iter j+5
    }
    // ---- iter 60 (steady) ----
    STEP(62, 2, 63, s0a, s0b, 0, 0, 1, s1a, s1b, 8)
    // ---- iter 61 (drain: no LOAD_B) ----
    ISSUE_A(63, 0);
    COMPUTE(1, 1);
    VMCNT(6);                 // B(62)+A(62) done
    WRITE_B(0, s2a, s2b);
    LGKM0;
    __builtin_amdgcn_s_barrier();
    // ---- iter 62 ----
    COMPUTE(2, 0);
    VMCNT(4);                 // B(63) done
    WRITE_B(1, s0a, s0b);
    LGKM0;
    __builtin_amdgcn_s_barrier();
    // ---- iter 63 ----
    VMCNT(0);                 // A(63) done
    COMPUTE(0, 1);

    #undef ISSUE_A
    #undef LOAD_B
    #undef WRITE_B
    #undef COMPUTE
    #undef VMCNT
    #undef LGKM0
    #undef STEP

    float* dst = parts + (size_t)s * (256 * 4096);
    #pragma unroll
    for (int mi = 0; mi < 4; ++mi) {
        #pragma unroll
        for (int ni = 0; ni < 4; ++ni) {
            int col = n0 + ni * 16 + l15;
            #pragma unroll
            for (int r = 0; r < 4; ++r) {
                int row = wave * 64 + mi * 16 + lk * 4 + r;
                dst[(size_t)row * 4096 + col] = acc[mi][ni][r];
            }
        }
    }
}

// ---- reduce partials + bias -> d_out ---------------------------------------
__global__ __launch_bounds__(256) void k_reduce(const float* __restrict__ parts,
                                                const float* __restrict__ linb,
                                                float* __restrict__ out) {
    int idx = blockIdx.x * 256 + threadIdx.x;
    float v = linb[idx & 4095];
    #pragma unroll
    for (int s = 0; s < 8; ++s) v += parts[(size_t)s * (256 * 4096) + idx];
    out[idx] = v;
}

extern "C" void kernel_launch(void* const* d_in, const int* in_sizes, int n_in,
                              void* d_out, int out_size, void* d_ws, size_t ws_size,
                              hipStream_t stream) {
    (void)in_sizes; (void)n_in; (void)out_size; (void)ws_size;
    const float* x   = (const float*)d_in[0];
    const int*   ei  = (const int*)d_in[1];
    const float* ea  = (const float*)d_in[2];
    /* d_in[3] = batch (unused, fixed layout) */
    const float* Wl  = (const float*)d_in[4];
    const float* Wr  = (const float*)d_in[5];
    const float* We  = (const float*)d_in[6];
    const float* att = (const float*)d_in[7];
    const float* bg  = (const float*)d_in[8];
    const float* W   = (const float*)d_in[9];
    const float* lb  = (const float*)d_in[10];
    float* out = (float*)d_out;

    char* p = (char*)d_ws;
    float* xl           = (float*)p;          p += 16777216;           // 16384x256 f32
    float* xr           = (float*)p;          p += 16777216;
    unsigned short* hb  = (unsigned short*)p; p += 8388608;            // 16384x256 bf16
    float* parts        = (float*)p;          p += 33554432;           // 8x256x4096 f32
    float* eapart       = (float*)p;          p += 16384;              // 256x16
    float* eeself       = (float*)p;          p += 1024;               // 256

    k_ea_part  <<<256,  256, 0, stream>>>(ea, eapart);
    k_ea_finish<<<1,    256, 0, stream>>>(eapart, We, eeself);
    k_xlr2     <<<dim3(256, 4), 256, 0, stream>>>(x, Wl, Wr, xl, xr);
    k_attn     <<<1024, 256, 0, stream>>>(ei, ea, eeself, att, We, xl, xr, bg, hb);
    k_gemm     <<<dim3(64, 8), 256, 0, stream>>>(hb, W, parts);
    k_reduce   <<<4096, 256, 0, stream>>>(parts, lb, out);
}

// Round 11
// 179.384 us; speedup vs baseline: 1.5294x; 1.0349x over previous
//
#include <hip/hip_runtime.h>
#include <hip/hip_bf16.h>

// Problem constants (fixed by reference)
#define N_NODES   16384
#define DEG       16
#define EDGES     262144          // N_NODES*DEG
#define HC        256             // HEADS*OUT_C
#define KDIM      16384           // 64 nodes * 256 feat
#define NEG_SLOPE 0.2f

typedef __attribute__((ext_vector_type(8))) short short8;   // 8 bf16
typedef __attribute__((ext_vector_type(4))) float floatx4;

static __device__ __forceinline__ unsigned short f2bf(float f) {
    union { __hip_bfloat16 h; unsigned short u; } c;
    c.h = __float2bfloat16(f);          // RNE
    return c.u;
}
static __device__ __forceinline__ unsigned int packbf2(float lo, float hi) {
    union { __hip_bfloat162 h2; unsigned int u; } c;
    c.h2 = __float22bfloat162_rn(make_float2(lo, hi));   // v_cvt_pk_bf16_f32
    return c.u;
}

// DPP row_shr add chain {1,2,4,8}: lane l15==15 holds the 16-lane sum.
template <int CTRL>
static __device__ __forceinline__ float dpp_add(float v) {
    int x = __builtin_amdgcn_update_dpp(0, __float_as_int(v), CTRL, 0xF, 0xF, true);
    return v + __int_as_float(x);
}

// ---- fused prep: blocks 0..255 = ea_part, 256..1279 = xlr2 -----------------
__global__ __launch_bounds__(256) void k_prep(const float* __restrict__ ea,
                                              float* __restrict__ part,
                                              const float* __restrict__ x,
                                              const float* __restrict__ Wl,
                                              const float* __restrict__ Wr,
                                              float* __restrict__ xl,
                                              float* __restrict__ xr) {
    __shared__ float s[256];                 // ea_part
    __shared__ unsigned short As[64][40];    // xlr2
    __shared__ unsigned int   Bs[128][18];
    int bid = blockIdx.x;
    int t = threadIdx.x;

    if (bid < 256) {   // ---- ea_part ----
        int b = bid;
        int col = t & 15, r0 = t >> 4;
        const float* base = ea + (size_t)b * 1024 * 16;
        float acc = 0.f;
        for (int r = r0; r < 1024; r += 16) acc += base[r * 16 + col];
        s[t] = acc; __syncthreads();
        for (int off = 128; off >= 16; off >>= 1) {
            if (t < off) s[t] += s[t + off];
            __syncthreads();
        }
        if (t < 16) part[b * 16 + t] = s[t];
        return;
    }

    // ---- xlr2 ----
    unsigned int* As32 = (unsigned int*)&As[0][0];
    int idx = bid - 256;
    int wave = t >> 6, lane = t & 63;
    int l15 = lane & 15, lk = lane >> 4;
    int wm = wave >> 1, wn = wave & 1;
    int m0 = (idx & 255) * 64;
    int n0 = (idx >> 8) * 128;
    const float* Wsel = (n0 < 256) ? Wl : Wr;
    int bc = n0 & 255;

    floatx4 acc[2][4];
    #pragma unroll
    for (int i = 0; i < 2; ++i)
        #pragma unroll
        for (int j = 0; j < 4; ++j)
            acc[i][j] = (floatx4)(0.f);

    int ar = t >> 2, ac = t & 3;
    int bkp = t >> 4, bcc = t & 15;

    for (int k0 = 0; k0 < 128; k0 += 32) {
        __syncthreads();
        {   // stage A: x[m0+r][k0 + ac*8 .. +7] -> bf16
            const float* gp = x + (size_t)(m0 + ar) * 128 + k0 + ac * 8;
            float4 v0 = *(const float4*)gp;
            float4 v1 = *(const float4*)(gp + 4);
            As32[ar * 20 + ac * 4 + 0] = packbf2(v0.x, v0.y);
            As32[ar * 20 + ac * 4 + 1] = packbf2(v0.z, v0.w);
            As32[ar * 20 + ac * 4 + 2] = packbf2(v1.x, v1.y);
            As32[ar * 20 + ac * 4 + 3] = packbf2(v1.z, v1.w);
        }
        {   // stage B
            const float* wp = Wsel + (size_t)(k0 + 2 * bkp) * 256 + bc + bcc * 8;
            float4 r0a = *(const float4*)wp;
            float4 r0b = *(const float4*)(wp + 4);
            float4 r1a = *(const float4*)(wp + 256);
            float4 r1b = *(const float4*)(wp + 260);
            Bs[bcc * 8 + 0][bkp] = packbf2(r0a.x, r1a.x);
            Bs[bcc * 8 + 1][bkp] = packbf2(r0a.y, r1a.y);
            Bs[bcc * 8 + 2][bkp] = packbf2(r0a.z, r1a.z);
            Bs[bcc * 8 + 3][bkp] = packbf2(r0a.w, r1a.w);
            Bs[bcc * 8 + 4][bkp] = packbf2(r0b.x, r1b.x);
            Bs[bcc * 8 + 5][bkp] = packbf2(r0b.y, r1b.y);
            Bs[bcc * 8 + 6][bkp] = packbf2(r0b.z, r1b.z);
            Bs[bcc * 8 + 7][bkp] = packbf2(r0b.w, r1b.w);
        }
        __syncthreads();
        short8 a[2], b[4];
        #pragma unroll
        for (int mi = 0; mi < 2; ++mi)
            a[mi] = *(const short8*)&As[wm * 32 + mi * 16 + l15][lk * 8];
        #pragma unroll
        for (int ni = 0; ni < 4; ++ni) {
            int nr = wn * 64 + ni * 16 + l15;
            union { uint2 u[2]; short8 v; } bb;
            bb.u[0] = *(const uint2*)&Bs[nr][lk * 4];
            bb.u[1] = *(const uint2*)&Bs[nr][lk * 4 + 2];
            b[ni] = bb.v;
        }
        #pragma unroll
        for (int mi = 0; mi < 2; ++mi)
            #pragma unroll
            for (int ni = 0; ni < 4; ++ni)
                acc[mi][ni] = __builtin_amdgcn_mfma_f32_16x16x32_bf16(a[mi], b[ni], acc[mi][ni], 0, 0, 0);
    }

    #pragma unroll
    for (int mi = 0; mi < 2; ++mi) {
        #pragma unroll
        for (int ni = 0; ni < 4; ++ni) {
            int n = n0 + wn * 64 + ni * 16 + l15;
            #pragma unroll
            for (int r = 0; r < 4; ++r) {
                int node = m0 + wm * 32 + mi * 16 + lk * 4 + r;
                if (n0 < 256) xl[(size_t)node * 256 + n]         = acc[mi][ni][r];
                else          xr[(size_t)node * 256 + (n - 256)] = acc[mi][ni][r];
            }
        }
    }
}

// ---- finish mean + ee_self = mean_ea @ W_e (parallel, 2-level tree) --------
__global__ __launch_bounds__(256) void k_ea_finish(const float* __restrict__ part,
                                                   const float* __restrict__ We,
                                                   float* __restrict__ eeself) {
    __shared__ float ps[16][16];
    __shared__ float mean[16];
    int t = threadIdx.x;
    int col = t & 15, bg = t >> 4;
    float a = 0.f;
    #pragma unroll
    for (int i = 0; i < 16; ++i)
        a += part[(bg + i * 16) * 16 + col];
    ps[bg][col] = a;
    __syncthreads();
    if (t < 16) {
        float m = 0.f;
        #pragma unroll
        for (int i = 0; i < 16; ++i) m += ps[i][t];
        mean[t] = m * (1.f / (float)EDGES);
    }
    __syncthreads();
    float acc = 0.f;
    #pragma unroll
    for (int d = 0; d < 16; ++d) acc += mean[d] * We[d * 256 + t];
    eeself[t] = acc;
}

// ---- fused GAT attention v7: g<->XCD co-location (ea L2 sharing) -----------
// Arithmetic is bit-identical to v6 (absmax canary 0.0078125 must hold).
__global__ __launch_bounds__(256) void k_attn(const int* __restrict__ ei,
                                              const float* __restrict__ ea,
                                              const float* __restrict__ eeself,
                                              const float* __restrict__ att,
                                              const float* __restrict__ We,
                                              const float* __restrict__ xl,
                                              const float* __restrict__ xr,
                                              const float* __restrict__ bg,
                                              unsigned short* __restrict__ hb) {
    __shared__ float xlS[64][68];    // permuted cols, pitch 68
    __shared__ float xrS[64][68];
    __shared__ float lgS[1088];
    __shared__ unsigned char srcS[1024];

    int t = threadIdx.x;
    // XCD co-location: the 4 head-blocks of graph g are {g, g+256, g+512, g+768},
    // all == g (mod 8) -> same XCD -> g's 64KB of ea is fetched once per XCD.
    int g = blockIdx.x & 255, h = blockIdx.x >> 8;
    int hc0 = h * 64;
    unsigned int* srcSu = (unsigned int*)srcS;

    {   // stage xl/xr head slices into PERMUTED layout
        int n = t >> 2, q4 = t & 3;
        const float* xlp = xl + ((size_t)(g * 64 + n)) * 256 + hc0 + q4 * 16;
        const float* xrp = xr + ((size_t)(g * 64 + n)) * 256 + hc0 + q4 * 16;
        #pragma unroll
        for (int i = 0; i < 4; ++i) {
            float4 vl = *(const float4*)(xlp + i * 4);
            float4 vr = *(const float4*)(xrp + i * 4);
            xlS[n][(i * 4 + 0) * 4 + q4] = vl.x;
            xlS[n][(i * 4 + 1) * 4 + q4] = vl.y;
            xlS[n][(i * 4 + 2) * 4 + q4] = vl.z;
            xlS[n][(i * 4 + 3) * 4 + q4] = vl.w;
            xrS[n][(i * 4 + 0) * 4 + q4] = vr.x;
            xrS[n][(i * 4 + 1) * 4 + q4] = vr.y;
            xrS[n][(i * 4 + 2) * 4 + q4] = vr.z;
            xrS[n][(i * 4 + 3) * 4 + q4] = vr.w;
        }
    }
    {   // stage local src indices, packed 4/uint
        int4 v = *(const int4*)(ei + (size_t)g * 1024 + t * 4);
        srcSu[t] = (unsigned int)(v.x & 63) | ((unsigned int)(v.y & 63) << 8) |
                   ((unsigned int)(v.z & 63) << 16) | ((unsigned int)(v.w & 63) << 24);
    }

    int wave = t >> 6, lane = t & 63;
    int q = lane >> 4, l15 = lane & 15;

    short8 wf[4];
    float  attv[4];
    #pragma unroll
    for (int nt = 0; nt < 4; ++nt) {
        attv[nt] = att[hc0 + nt * 16 + l15];
        if (q < 2) {
            const float* wp = We + (size_t)(q * 8) * 256 + hc0 + nt * 16 + l15;
            float w0 = wp[0*256], w1 = wp[1*256], w2 = wp[2*256], w3 = wp[3*256];
            float w4 = wp[4*256], w5 = wp[5*256], w6 = wp[6*256], w7 = wp[7*256];
            union { unsigned int u[4]; short8 v; } bb;
            bb.u[0] = packbf2(w0, w1);
            bb.u[1] = packbf2(w2, w3);
            bb.u[2] = packbf2(w4, w5);
            bb.u[3] = packbf2(w6, w7);
            wf[nt] = bb.v;
        } else {
            wf[nt] = (short8)0;
        }
    }
    __syncthreads();

    for (int b = wave; b < 16; b += 4) {
        short8 af[4];
        #pragma unroll
        for (int mt = 0; mt < 4; ++mt) {
            if (q < 2) {
                const float* ep = ea + ((size_t)(g * 1024 + b * 64 + mt * 16 + l15)) * 16 + q * 8;
                float4 v0 = *(const float4*)ep;
                float4 v1 = *(const float4*)(ep + 4);
                union { unsigned int u[4]; short8 v; } bb;
                bb.u[0] = packbf2(v0.x, v0.y);
                bb.u[1] = packbf2(v0.z, v0.w);
                bb.u[2] = packbf2(v1.x, v1.y);
                bb.u[3] = packbf2(v1.z, v1.w);
                af[mt] = bb.v;
            } else {
                af[mt] = (short8)0;
            }
        }
        floatx4 acc[4][4];
        #pragma unroll
        for (int mt = 0; mt < 4; ++mt)
            #pragma unroll
            for (int nt = 0; nt < 4; ++nt)
                acc[mt][nt] = __builtin_amdgcn_mfma_f32_16x16x32_bf16(af[mt], wf[nt], (floatx4)(0.f), 0, 0, 0);

        #pragma unroll
        for (int mt = 0; mt < 4; ++mt) {
            float4 xrv = *(const float4*)&xrS[b * 4 + mt][l15 * 4];
            unsigned int sw = srcSu[b * 16 + mt * 4 + q];
            int sr[4] = {(int)(sw & 255), (int)((sw >> 8) & 255),
                         (int)((sw >> 16) & 255), (int)(sw >> 24)};
            float lsum[4];
            #pragma unroll
            for (int r = 0; r < 4; ++r) {
                float4 xlv = *(const float4*)&xlS[sr[r]][l15 * 4];
                float f, acc_sum = 0.f;
                f = acc[mt][0][r] + xlv.x + xrv.x; f = fmaxf(f, NEG_SLOPE * f); acc_sum += f * attv[0];
                f = acc[mt][1][r] + xlv.y + xrv.y; f = fmaxf(f, NEG_SLOPE * f); acc_sum += f * attv[1];
                f = acc[mt][2][r] + xlv.z + xrv.z; f = fmaxf(f, NEG_SLOPE * f); acc_sum += f * attv[2];
                f = acc[mt][3][r] + xlv.w + xrv.w; f = fmaxf(f, NEG_SLOPE * f); acc_sum += f * attv[3];
                lsum[r] = acc_sum;
            }
            #pragma unroll
            for (int r = 0; r < 4; ++r) {
                float v = lsum[r];
                v = dpp_add<0x111>(v);
                v = dpp_add<0x112>(v);
                v = dpp_add<0x114>(v);
                v = dpp_add<0x118>(v);
                if (l15 == 15) lgS[b * 64 + mt * 16 + q * 4 + r] = v;
            }
        }
    }

    {   // self-loop batch (permuted indexing)
        int n = wave * 16 + l15;
        float sum = 0.f;
        const float* eep = eeself + hc0 + q * 16;
        const float* ap  = att + hc0 + q * 16;
        #pragma unroll
        for (int i = 0; i < 4; ++i) {
            float4 ev = *(const float4*)(eep + i * 4);
            float4 av = *(const float4*)(ap + i * 4);
            #pragma unroll
            for (int j = 0; j < 4; ++j) {
                int p = (i * 4 + j) * 4 + q;
                float e = (j == 0) ? ev.x : (j == 1) ? ev.y : (j == 2) ? ev.z : ev.w;
                float a = (j == 0) ? av.x : (j == 1) ? av.y : (j == 2) ? av.z : av.w;
                float f = xlS[n][p] + xrS[n][p] + e;
                f = fmaxf(f, NEG_SLOPE * f);
                sum += f * a;
            }
        }
        sum += __shfl_xor(sum, 16);
        sum += __shfl_xor(sum, 32);
        if (q == 0) lgS[1024 + n] = sum;
    }
    __syncthreads();

    if (t < 64) {
        float lg[17];
        #pragma unroll
        for (int j = 0; j < 16; ++j) lg[j] = lgS[t * 16 + j];
        lg[16] = lgS[1024 + t];
        float m = lg[0];
        #pragma unroll
        for (int j = 1; j < 17; ++j) m = fmaxf(m, lg[j]);
        float ex[17], ssum = 0.f;
        #pragma unroll
        for (int j = 0; j < 17; ++j) { ex[j] = __expf(lg[j] - m); ssum += ex[j]; }
        float inv = 1.f / (17.f * ssum);
        #pragma unroll
        for (int j = 0; j < 16; ++j) lgS[t * 16 + j] = ex[j] * inv;
        lgS[1024 + t] = ex[16] * inv;
    }
    __syncthreads();

    {   // aggregation
        int c = lane;
        int pc = (c & 15) * 4 + (c >> 4);
        float bgv = bg[hc0 + c];
        for (int n = wave * 16; n < wave * 16 + 16; ++n) {
            float4 al0 = *(const float4*)&lgS[n * 16];
            float4 al1 = *(const float4*)&lgS[n * 16 + 4];
            float4 al2 = *(const float4*)&lgS[n * 16 + 8];
            float4 al3 = *(const float4*)&lgS[n * 16 + 12];
            unsigned int w0 = srcSu[n * 4 + 0], w1 = srcSu[n * 4 + 1];
            unsigned int w2 = srcSu[n * 4 + 2], w3 = srcSu[n * 4 + 3];
            float a0 = lgS[1024 + n] * xlS[n][pc];
            float a1 = 0.f;
            a0 += al0.x * xlS[w0 & 255][pc];        a1 += al0.y * xlS[(w0 >> 8) & 255][pc];
            a0 += al0.z * xlS[(w0 >> 16) & 255][pc]; a1 += al0.w * xlS[w0 >> 24][pc];
            a0 += al1.x * xlS[w1 & 255][pc];        a1 += al1.y * xlS[(w1 >> 8) & 255][pc];
            a0 += al1.z * xlS[(w1 >> 16) & 255][pc]; a1 += al1.w * xlS[w1 >> 24][pc];
            a0 += al2.x * xlS[w2 & 255][pc];        a1 += al2.y * xlS[(w2 >> 8) & 255][pc];
            a0 += al2.z * xlS[(w2 >> 16) & 255][pc]; a1 += al2.w * xlS[w2 >> 24][pc];
            a0 += al3.x * xlS[w3 & 255][pc];        a1 += al3.y * xlS[(w3 >> 8) & 255][pc];
            a0 += al3.z * xlS[(w3 >> 16) & 255][pc]; a1 += al3.w * xlS[w3 >> 24][pc];
            float val = a0 + a1 + bgv;
            hb[((size_t)(g * 64 + n)) * 256 + hc0 + c] = f2bf(val);
        }
    }
}

// ---- big GEMM v9: K-slice <-> XCD co-location (A slice L2-resident) --------
// bid&7 = K-split s: all 64 blocks of slice s land on XCD s (round-robin %8),
// so each XCD's A working set is 1 MB (fits 4 MB L2) instead of 8.4 MB.
__global__ __launch_bounds__(256) void k_gemm(const unsigned short* __restrict__ hb,
                                              const float* __restrict__ W,
                                              float* __restrict__ parts) {
    __shared__ unsigned short As[3][256 * 32];
    __shared__ unsigned int   Bs[2][64][18];

    int t = threadIdx.x;
    int wave = t >> 6, lane = t & 63;
    int l15 = lane & 15, lk = lane >> 4;
    int bid = blockIdx.x;
    int s  = bid & 7;              // K-split == XCD id
    int n0 = (bid >> 3) * 64;      // N-tile
    int kbase = s * 2048;

    floatx4 acc[4][4];
    #pragma unroll
    for (int i = 0; i < 4; ++i)
        #pragma unroll
        for (int j = 0; j < 4; ++j)
            acc[i][j] = (floatx4)(0.f);

    int gc = ((lane & 3) - ((lane >> 3) & 3)) & 3;
    const unsigned short* a_src =
        hb + (size_t)(wave * 64 + (lane >> 2)) * KDIM + kbase + gc * 8;
    int ap_off[4];
    #pragma unroll
    for (int mi = 0; mi < 4; ++mi)
        ap_off[mi] = (wave * 64 + mi * 16 + l15) * 32 + (((lk + (l15 >> 1)) & 3) * 8);

    int bkp = t >> 4;
    int bc8 = t & 15;
    const float* b_src = W + (size_t)(kbase + 2 * bkp) * 4096 + n0 + bc8 * 4;

    #define ISSUE_A(step, buf)                                                   \
        {                                                                        \
            const unsigned short* gp_ = a_src + (size_t)(step) * 32;             \
            _Pragma("unroll")                                                    \
            for (int i_ = 0; i_ < 4; ++i_) {                                     \
                __builtin_amdgcn_global_load_lds(                                \
                    (const __attribute__((address_space(1))) unsigned int*)      \
                        (gp_ + (size_t)i_ * 16 * KDIM),                          \
                    (__attribute__((address_space(3))) unsigned int*)            \
                        &As[buf][(wave * 64 + i_ * 16) * 32],                    \
                    16, 0, 0);                                                   \
            }                                                                    \
        }
    #define LOAD_B(step, r0, r1)                                                 \
        {                                                                        \
            const float* wp_ = b_src + (size_t)(step) * 32 * 4096;               \
            r0 = *(const float4*)wp_;                                            \
            r1 = *(const float4*)(wp_ + 4096);                                   \
        }
    #define WRITE_B(buf, r0, r1)                                                 \
        {                                                                        \
            Bs[buf][bc8 * 4 + 0][bkp] = packbf2(r0.x, r1.x);                     \
            Bs[buf][bc8 * 4 + 1][bkp] = packbf2(r0.y, r1.y);                     \
            Bs[buf][bc8 * 4 + 2][bkp] = packbf2(r0.z, r1.z);                     \
            Bs[buf][bc8 * 4 + 3][bkp] = packbf2(r0.w, r1.w);                     \
        }
    #define COMPUTE(abuf, bbuf)                                                  \
        {                                                                        \
            short8 a_[4], b_[4];                                                 \
            _Pragma("unroll")                                                    \
            for (int mi = 0; mi < 4; ++mi)                                       \
                a_[mi] = *(const short8*)&As[abuf][ap_off[mi]];                  \
            _Pragma("unroll")                                                    \
            for (int ni = 0; ni < 4; ++ni) {                                     \
                int nr_ = ni * 16 + l15;                                         \
                union { uint2 u[2]; short8 v; } bb_;                             \
                bb_.u[0] = *(const uint2*)&Bs[bbuf][nr_][lk * 4];                \
                bb_.u[1] = *(const uint2*)&Bs[bbuf][nr_][lk * 4 + 2];            \
                b_[ni] = bb_.v;                                                  \
            }                                                                    \
            __builtin_amdgcn_s_setprio(1);                                       \
            _Pragma("unroll")                                                    \
            for (int mi = 0; mi < 4; ++mi)                                       \
                _Pragma("unroll")                                                \
                for (int ni = 0; ni < 4; ++ni)                                   \
                    acc[mi][ni] = __builtin_amdgcn_mfma_f32_16x16x32_bf16(       \
                        a_[mi], b_[ni], acc[mi][ni], 0, 0, 0);                   \
            __builtin_amdgcn_s_setprio(0);                                       \
        }
    #define VMCNT(n) __builtin_amdgcn_sched_barrier(0);                          \
                     asm volatile("s_waitcnt vmcnt(" #n ")" ::: "memory");       \
                     __builtin_amdgcn_sched_barrier(0)
    #define LGKM0    asm volatile("s_waitcnt lgkmcnt(0)" ::: "memory");          \
                     __builtin_amdgcn_sched_barrier(0)
    #define STEP(jA, abufI, jB, ldS0, ldS1, cA, cB, wB, wS0, wS1, VM)            \
        ISSUE_A(jA, abufI);                                                      \
        LOAD_B(jB, ldS0, ldS1);                                                  \
        COMPUTE(cA, cB);                                                         \
        VMCNT(VM);                                                               \
        WRITE_B(wB, wS0, wS1);                                                   \
        LGKM0;                                                                   \
        __builtin_amdgcn_s_barrier();

    float4 s0a, s0b, s1a, s1b, s2a, s2b;

    // ---- prologue ----
    ISSUE_A(0, 0);
    LOAD_B(0, s0a, s0b);
    ISSUE_A(1, 1);
    LOAD_B(1, s1a, s1b);
    LOAD_B(2, s2a, s2b);
    VMCNT(8);
    WRITE_B(0, s0a, s0b);
    LGKM0;
    __builtin_amdgcn_s_barrier();

    // ---- steady: iters 0..59, unrolled by 6 ----
    for (int j = 0; j < 60; j += 6) {
        STEP(j + 2, 2, j + 3, s0a, s0b, 0, 0, 1, s1a, s1b, 8)
        STEP(j + 3, 0, j + 4, s1a, s1b, 1, 1, 0, s2a, s2b, 8)
        STEP(j + 4, 1, j + 5, s2a, s2b, 2, 0, 1, s0a, s0b, 8)
        STEP(j + 5, 2, j + 6, s0a, s0b, 0, 1, 0, s1a, s1b, 8)
        STEP(j + 6, 0, j + 7, s1a, s1b, 1, 0, 1, s2a, s2b, 8)
        STEP(j + 7, 1, j + 8, s2a, s2b, 2, 1, 0, s0a, s0b, 8)
    }
    // ---- iter 60 ----
    STEP(62, 2, 63, s0a, s0b, 0, 0, 1, s1a, s1b, 8)
    // ---- iter 61 (drain) ----
    ISSUE_A(63, 0);
    COMPUTE(1, 1);
    VMCNT(6);
    WRITE_B(0, s2a, s2b);
    LGKM0;
    __builtin_amdgcn_s_barrier();
    // ---- iter 62 ----
    COMPUTE(2, 0);
    VMCNT(4);
    WRITE_B(1, s0a, s0b);
    LGKM0;
    __builtin_amdgcn_s_barrier();
    // ---- iter 63 ----
    VMCNT(0);
    COMPUTE(0, 1);

    #undef ISSUE_A
    #undef LOAD_B
    #undef WRITE_B
    #undef COMPUTE
    #undef VMCNT
    #undef LGKM0
    #undef STEP

    float* dst = parts + (size_t)s * (256 * 4096);
    #pragma unroll
    for (int mi = 0; mi < 4; ++mi) {
        #pragma unroll
        for (int ni = 0; ni < 4; ++ni) {
            int col = n0 + ni * 16 + l15;
            #pragma unroll
            for (int r = 0; r < 4; ++r) {
                int row = wave * 64 + mi * 16 + lk * 4 + r;
                dst[(size_t)row * 4096 + col] = acc[mi][ni][r];
            }
        }
    }
}

// ---- reduce partials + bias -> d_out ---------------------------------------
__global__ __launch_bounds__(256) void k_reduce(const float* __restrict__ parts,
                                                const float* __restrict__ linb,
                                                float* __restrict__ out) {
    int idx = blockIdx.x * 256 + threadIdx.x;
    float v = linb[idx & 4095];
    #pragma unroll
    for (int s = 0; s < 8; ++s) v += parts[(size_t)s * (256 * 4096) + idx];
    out[idx] = v;
}

extern "C" void kernel_launch(void* const* d_in, const int* in_sizes, int n_in,
                              void* d_out, int out_size, void* d_ws, size_t ws_size,
                              hipStream_t stream) {
    (void)in_sizes; (void)n_in; (void)out_size; (void)ws_size;
    const float* x   = (const float*)d_in[0];
    const int*   ei  = (const int*)d_in[1];
    const float* ea  = (const float*)d_in[2];
    /* d_in[3] = batch (unused, fixed layout) */
    const float* Wl  = (const float*)d_in[4];
    const float* Wr  = (const float*)d_in[5];
    const float* We  = (const float*)d_in[6];
    const float* att = (const float*)d_in[7];
    const float* bg  = (const float*)d_in[8];
    const float* W   = (const float*)d_in[9];
    const float* lb  = (const float*)d_in[10];
    float* out = (float*)d_out;

    char* p = (char*)d_ws;
    float* xl           = (float*)p;          p += 16777216;           // 16384x256 f32
    float* xr           = (float*)p;          p += 16777216;
    unsigned short* hb  = (unsigned short*)p; p += 8388608;            // 16384x256 bf16
    float* parts        = (float*)p;          p += 33554432;           // 8x256x4096 f32
    float* eapart       = (float*)p;          p += 16384;              // 256x16
    float* eeself       = (float*)p;          p += 1024;               // 256

    k_prep     <<<1280, 256, 0, stream>>>(ea, eapart, x, Wl, Wr, xl, xr);
    k_ea_finish<<<1,    256, 0, stream>>>(eapart, We, eeself);
    k_attn     <<<1024, 256, 0, stream>>>(ei, ea, eeself, att, We, xl, xr, bg, hb);
    k_gemm     <<<512,  256, 0, stream>>>(hb, W, parts);
    k_reduce   <<<4096, 256, 0, stream>>>(parts, lb, out);
}

// Round 12
// 156.190 us; speedup vs baseline: 1.7565x; 1.1485x over previous
//
#include <hip/hip_runtime.h>
#include <hip/hip_bf16.h>

// Problem constants (fixed by reference)
#define N_NODES   16384
#define DEG       16
#define EDGES     262144          // N_NODES*DEG
#define HC        256             // HEADS*OUT_C
#define KDIM      16384           // 64 nodes * 256 feat
#define NEG_SLOPE 0.2f

typedef __attribute__((ext_vector_type(8))) short short8;   // 8 bf16
typedef __attribute__((ext_vector_type(4))) float floatx4;

static __device__ __forceinline__ unsigned short f2bf(float f) {
    union { __hip_bfloat16 h; unsigned short u; } c;
    c.h = __float2bfloat16(f);          // RNE
    return c.u;
}
static __device__ __forceinline__ unsigned int packbf2(float lo, float hi) {
    union { __hip_bfloat162 h2; unsigned int u; } c;
    c.h2 = __float22bfloat162_rn(make_float2(lo, hi));   // v_cvt_pk_bf16_f32
    return c.u;
}

// DPP row_shr add chain {1,2,4,8}: lane l15==15 holds the 16-lane sum.
template <int CTRL>
static __device__ __forceinline__ float dpp_add(float v) {
    int x = __builtin_amdgcn_update_dpp(0, __float_as_int(v), CTRL, 0xF, 0xF, true);
    return v + __int_as_float(x);
}

// ---- mean(edge_attr) partial sums: 256 blocks x 1024 rows -----------------
__global__ __launch_bounds__(256) void k_ea_part(const float* __restrict__ ea,
                                                 float* __restrict__ part) {
    __shared__ float s[256];
    int b = blockIdx.x, t = threadIdx.x;
    int col = t & 15, r0 = t >> 4;
    const float* base = ea + (size_t)b * 1024 * 16;
    float acc = 0.f;
    for (int r = r0; r < 1024; r += 16) acc += base[r * 16 + col];
    s[t] = acc; __syncthreads();
    for (int off = 128; off >= 16; off >>= 1) {
        if (t < off) s[t] += s[t + off];
        __syncthreads();
    }
    if (t < 16) part[b * 16 + t] = s[t];
}

// ---- fused GAT attention v8: xlr mini-GEMM + eeself + logits + softmax + agg
// All arithmetic bit-identical to the R11 pipeline (canary 0.0078125).
// LDS = 17408*2 + 5376 + 64 + 256 = 40512 B -> 4 blocks/CU.
__global__ __launch_bounds__(256, 4) void k_attn(const int* __restrict__ ei,
                                                 const float* __restrict__ ea,
                                                 const float* __restrict__ eapart,
                                                 const float* __restrict__ att,
                                                 const float* __restrict__ We,
                                                 const float* __restrict__ x,
                                                 const float* __restrict__ Wl,
                                                 const float* __restrict__ Wr,
                                                 const float* __restrict__ bg,
                                                 unsigned short* __restrict__ hb) {
    __shared__ float xlS[64][68];    // permuted cols, pitch 68
    __shared__ float xrS[64][68];
    __shared__ __align__(16) char uni[5376];   // ps | Bs[64][18] | lgS+srcS
    __shared__ float mean[16];
    __shared__ float eeselfS[64];

    float* lgS = (float*)uni;                              // [1088]
    unsigned int* srcSu = (unsigned int*)(uni + 4352);     // [256] packed bytes
    unsigned char* srcSb = (unsigned char*)(uni + 4352);
    unsigned int* BsU = (unsigned int*)uni;                // Bs[col][kp] col<64 kp<16 pitch18
    float (*ps)[16] = (float(*)[16])uni;                   // [16][16]
    (void)srcSb;

    int t = threadIdx.x;
    // XCD co-location: 4 head-blocks of graph g are g, g+256, g+512, g+768 (same XCD).
    int g = blockIdx.x & 255, h = blockIdx.x >> 8;
    int hc0 = h * 64;

    int wave = t >> 6, lane = t & 63;
    int q = lane >> 4, l15 = lane & 15, lk = lane >> 4;  // lk == q (0..3)

    // ---- phase E: mean(ea) + eeself (exact ea_finish replication) ----
    {
        int col = t & 15, bgi = t >> 4;
        float a = 0.f;
        #pragma unroll
        for (int i = 0; i < 16; ++i)
            a += eapart[(bgi + i * 16) * 16 + col];
        ps[bgi][col] = a;
        __syncthreads();
        if (t < 16) {
            float m = 0.f;
            #pragma unroll
            for (int i = 0; i < 16; ++i) m += ps[i][t];
            mean[t] = m * (1.f / (float)EDGES);
        }
        __syncthreads();
        if (t < 64) {
            float acc = 0.f;
            #pragma unroll
            for (int d = 0; d < 16; ++d) acc += mean[d] * We[d * 256 + hc0 + t];
            eeselfS[t] = acc;
        }
        __syncthreads();   // uni (ps) free; eeselfS visible later
    }

    // ---- phase X: xl|xr mini-GEMM (bit-identical to k_xlr2) ----
    {
        int wm = wave;   // M-tile: rows wm*16 .. wm*16+15
        const float* xrow = x + ((size_t)(g * 64 + wm * 16 + l15)) * 128 + lk * 8;
        floatx4 accL[4], accR[4];
        #pragma unroll
        for (int i = 0; i < 4; ++i) { accL[i] = (floatx4)(0.f); accR[i] = (floatx4)(0.f); }

        int bkp = t >> 4, bc4 = t & 15;   // B staging: k-pair, 4-col group

        for (int k0 = 0; k0 < 128; k0 += 32) {
            // A-frag from global (same packbf2 pairing as k_xlr2's As)
            float4 xv0 = *(const float4*)(xrow + k0);
            float4 xv1 = *(const float4*)(xrow + k0 + 4);
            union { unsigned int u[4]; short8 v; } aa;
            aa.u[0] = packbf2(xv0.x, xv0.y);
            aa.u[1] = packbf2(xv0.z, xv0.w);
            aa.u[2] = packbf2(xv1.x, xv1.y);
            aa.u[3] = packbf2(xv1.z, xv1.w);
            short8 af = aa.v;

            #pragma unroll
            for (int side = 0; side < 2; ++side) {
                const float* Wsel = side ? Wr : Wl;
                __syncthreads();   // Bs free
                {   // stage 64 cols of Wsel head-slice, K=32 (pairs)
                    const float* wp = Wsel + (size_t)(k0 + 2 * bkp) * 256 + hc0 + bc4 * 4;
                    float4 r0 = *(const float4*)wp;
                    float4 r1 = *(const float4*)(wp + 256);
                    BsU[(bc4 * 4 + 0) * 18 + bkp] = packbf2(r0.x, r1.x);
                    BsU[(bc4 * 4 + 1) * 18 + bkp] = packbf2(r0.y, r1.y);
                    BsU[(bc4 * 4 + 2) * 18 + bkp] = packbf2(r0.z, r1.z);
                    BsU[(bc4 * 4 + 3) * 18 + bkp] = packbf2(r0.w, r1.w);
                }
                __syncthreads();
                #pragma unroll
                for (int ni = 0; ni < 4; ++ni) {
                    int nr = ni * 16 + l15;
                    union { uint2 u[2]; short8 v; } bb;
                    bb.u[0] = *(const uint2*)&BsU[nr * 18 + lk * 4];
                    bb.u[1] = *(const uint2*)&BsU[nr * 18 + lk * 4 + 2];
                    if (side == 0)
                        accL[ni] = __builtin_amdgcn_mfma_f32_16x16x32_bf16(af, bb.v, accL[ni], 0, 0, 0);
                    else
                        accR[ni] = __builtin_amdgcn_mfma_f32_16x16x32_bf16(af, bb.v, accR[ni], 0, 0, 0);
                }
            }
        }
        // write to permuted LDS: logical col c = ni*16+l15 -> pc = l15*4 + ni
        #pragma unroll
        for (int ni = 0; ni < 4; ++ni) {
            #pragma unroll
            for (int r = 0; r < 4; ++r) {
                int node = wm * 16 + lk * 4 + r;
                xlS[node][l15 * 4 + ni] = accL[ni][r];
                xrS[node][l15 * 4 + ni] = accR[ni][r];
            }
        }
    }
    __syncthreads();   // xlS/xrS complete; Bs reads done -> uni reusable

    {   // stage local src indices, packed 4/uint (into uni+4352)
        int4 v = *(const int4*)(ei + (size_t)g * 1024 + t * 4);
        srcSu[t] = (unsigned int)(v.x & 63) | ((unsigned int)(v.y & 63) << 8) |
                   ((unsigned int)(v.z & 63) << 16) | ((unsigned int)(v.w & 63) << 24);
    }

    // We head-slice frags + att (registers)
    short8 wf[4];
    float  attv[4];
    #pragma unroll
    for (int nt = 0; nt < 4; ++nt) {
        attv[nt] = att[hc0 + nt * 16 + l15];
        if (q < 2) {
            const float* wp = We + (size_t)(q * 8) * 256 + hc0 + nt * 16 + l15;
            float w0 = wp[0*256], w1 = wp[1*256], w2 = wp[2*256], w3 = wp[3*256];
            float w4 = wp[4*256], w5 = wp[5*256], w6 = wp[6*256], w7 = wp[7*256];
            union { unsigned int u[4]; short8 v; } bb;
            bb.u[0] = packbf2(w0, w1);
            bb.u[1] = packbf2(w2, w3);
            bb.u[2] = packbf2(w4, w5);
            bb.u[3] = packbf2(w6, w7);
            wf[nt] = bb.v;
        } else {
            wf[nt] = (short8)0;
        }
    }
    __syncthreads();   // srcSu visible

    // ---- edge-logit batches ----
    for (int b = wave; b < 16; b += 4) {
        short8 af[4];
        #pragma unroll
        for (int mt = 0; mt < 4; ++mt) {
            if (q < 2) {
                const float* ep = ea + ((size_t)(g * 1024 + b * 64 + mt * 16 + l15)) * 16 + q * 8;
                float4 v0 = *(const float4*)ep;
                float4 v1 = *(const float4*)(ep + 4);
                union { unsigned int u[4]; short8 v; } bb;
                bb.u[0] = packbf2(v0.x, v0.y);
                bb.u[1] = packbf2(v0.z, v0.w);
                bb.u[2] = packbf2(v1.x, v1.y);
                bb.u[3] = packbf2(v1.z, v1.w);
                af[mt] = bb.v;
            } else {
                af[mt] = (short8)0;
            }
        }
        floatx4 acc[4][4];
        #pragma unroll
        for (int mt = 0; mt < 4; ++mt)
            #pragma unroll
            for (int nt = 0; nt < 4; ++nt)
                acc[mt][nt] = __builtin_amdgcn_mfma_f32_16x16x32_bf16(af[mt], wf[nt], (floatx4)(0.f), 0, 0, 0);

        #pragma unroll
        for (int mt = 0; mt < 4; ++mt) {
            float4 xrv = *(const float4*)&xrS[b * 4 + mt][l15 * 4];
            unsigned int sw = srcSu[b * 16 + mt * 4 + q];
            int sr[4] = {(int)(sw & 255), (int)((sw >> 8) & 255),
                         (int)((sw >> 16) & 255), (int)(sw >> 24)};
            float lsum[4];
            #pragma unroll
            for (int r = 0; r < 4; ++r) {
                float4 xlv = *(const float4*)&xlS[sr[r]][l15 * 4];
                float f, acc_sum = 0.f;
                f = acc[mt][0][r] + xlv.x + xrv.x; f = fmaxf(f, NEG_SLOPE * f); acc_sum += f * attv[0];
                f = acc[mt][1][r] + xlv.y + xrv.y; f = fmaxf(f, NEG_SLOPE * f); acc_sum += f * attv[1];
                f = acc[mt][2][r] + xlv.z + xrv.z; f = fmaxf(f, NEG_SLOPE * f); acc_sum += f * attv[2];
                f = acc[mt][3][r] + xlv.w + xrv.w; f = fmaxf(f, NEG_SLOPE * f); acc_sum += f * attv[3];
                lsum[r] = acc_sum;
            }
            #pragma unroll
            for (int r = 0; r < 4; ++r) {
                float v = lsum[r];
                v = dpp_add<0x111>(v);
                v = dpp_add<0x112>(v);
                v = dpp_add<0x114>(v);
                v = dpp_add<0x118>(v);
                if (l15 == 15) lgS[b * 64 + mt * 16 + q * 4 + r] = v;
            }
        }
    }

    {   // self-loop batch (eeself from LDS, bit-identical values)
        int n = wave * 16 + l15;
        float sum = 0.f;
        #pragma unroll
        for (int i = 0; i < 4; ++i) {
            float4 ev = *(const float4*)&eeselfS[q * 16 + i * 4];
            float4 av = *(const float4*)(att + hc0 + q * 16 + i * 4);
            #pragma unroll
            for (int j = 0; j < 4; ++j) {
                int p = (i * 4 + j) * 4 + q;
                float e = (j == 0) ? ev.x : (j == 1) ? ev.y : (j == 2) ? ev.z : ev.w;
                float a = (j == 0) ? av.x : (j == 1) ? av.y : (j == 2) ? av.z : av.w;
                float f = xlS[n][p] + xrS[n][p] + e;
                f = fmaxf(f, NEG_SLOPE * f);
                sum += f * a;
            }
        }
        sum += __shfl_xor(sum, 16);
        sum += __shfl_xor(sum, 32);
        if (q == 0) lgS[1024 + n] = sum;
    }
    __syncthreads();

    if (t < 64) {
        float lg[17];
        #pragma unroll
        for (int j = 0; j < 16; ++j) lg[j] = lgS[t * 16 + j];
        lg[16] = lgS[1024 + t];
        float m = lg[0];
        #pragma unroll
        for (int j = 1; j < 17; ++j) m = fmaxf(m, lg[j]);
        float ex[17], ssum = 0.f;
        #pragma unroll
        for (int j = 0; j < 17; ++j) { ex[j] = __expf(lg[j] - m); ssum += ex[j]; }
        float inv = 1.f / (17.f * ssum);
        #pragma unroll
        for (int j = 0; j < 16; ++j) lgS[t * 16 + j] = ex[j] * inv;
        lgS[1024 + t] = ex[16] * inv;
    }
    __syncthreads();

    {   // aggregation
        int c = lane;
        int pc = (c & 15) * 4 + (c >> 4);
        float bgv = bg[hc0 + c];
        for (int n = wave * 16; n < wave * 16 + 16; ++n) {
            float4 al0 = *(const float4*)&lgS[n * 16];
            float4 al1 = *(const float4*)&lgS[n * 16 + 4];
            float4 al2 = *(const float4*)&lgS[n * 16 + 8];
            float4 al3 = *(const float4*)&lgS[n * 16 + 12];
            unsigned int w0 = srcSu[n * 4 + 0], w1 = srcSu[n * 4 + 1];
            unsigned int w2 = srcSu[n * 4 + 2], w3 = srcSu[n * 4 + 3];
            float a0 = lgS[1024 + n] * xlS[n][pc];
            float a1 = 0.f;
            a0 += al0.x * xlS[w0 & 255][pc];        a1 += al0.y * xlS[(w0 >> 8) & 255][pc];
            a0 += al0.z * xlS[(w0 >> 16) & 255][pc]; a1 += al0.w * xlS[w0 >> 24][pc];
            a0 += al1.x * xlS[w1 & 255][pc];        a1 += al1.y * xlS[(w1 >> 8) & 255][pc];
            a0 += al1.z * xlS[(w1 >> 16) & 255][pc]; a1 += al1.w * xlS[w1 >> 24][pc];
            a0 += al2.x * xlS[w2 & 255][pc];        a1 += al2.y * xlS[(w2 >> 8) & 255][pc];
            a0 += al2.z * xlS[(w2 >> 16) & 255][pc]; a1 += al2.w * xlS[w2 >> 24][pc];
            a0 += al3.x * xlS[w3 & 255][pc];        a1 += al3.y * xlS[(w3 >> 8) & 255][pc];
            a0 += al3.z * xlS[(w3 >> 16) & 255][pc]; a1 += al3.w * xlS[w3 >> 24][pc];
            float val = a0 + a1 + bgv;
            hb[((size_t)(g * 64 + n)) * 256 + hc0 + c] = f2bf(val);
        }
    }
}

// ---- big GEMM v9: K-slice <-> XCD co-location (A slice L2-resident) --------
__global__ __launch_bounds__(256) void k_gemm(const unsigned short* __restrict__ hb,
                                              const float* __restrict__ W,
                                              float* __restrict__ parts) {
    __shared__ unsigned short As[3][256 * 32];
    __shared__ unsigned int   Bs[2][64][18];

    int t = threadIdx.x;
    int wave = t >> 6, lane = t & 63;
    int l15 = lane & 15, lk = lane >> 4;
    int bid = blockIdx.x;
    int s  = bid & 7;              // K-split == XCD id
    int n0 = (bid >> 3) * 64;      // N-tile
    int kbase = s * 2048;

    floatx4 acc[4][4];
    #pragma unroll
    for (int i = 0; i < 4; ++i)
        #pragma unroll
        for (int j = 0; j < 4; ++j)
            acc[i][j] = (floatx4)(0.f);

    int gc = ((lane & 3) - ((lane >> 3) & 3)) & 3;
    const unsigned short* a_src =
        hb + (size_t)(wave * 64 + (lane >> 2)) * KDIM + kbase + gc * 8;
    int ap_off[4];
    #pragma unroll
    for (int mi = 0; mi < 4; ++mi)
        ap_off[mi] = (wave * 64 + mi * 16 + l15) * 32 + (((lk + (l15 >> 1)) & 3) * 8);

    int bkp = t >> 4;
    int bc8 = t & 15;
    const float* b_src = W + (size_t)(kbase + 2 * bkp) * 4096 + n0 + bc8 * 4;

    #define ISSUE_A(step, buf)                                                   \
        {                                                                        \
            const unsigned short* gp_ = a_src + (size_t)(step) * 32;             \
            _Pragma("unroll")                                                    \
            for (int i_ = 0; i_ < 4; ++i_) {                                     \
                __builtin_amdgcn_global_load_lds(                                \
                    (const __attribute__((address_space(1))) unsigned int*)      \
                        (gp_ + (size_t)i_ * 16 * KDIM),                          \
                    (__attribute__((address_space(3))) unsigned int*)            \
                        &As[buf][(wave * 64 + i_ * 16) * 32],                    \
                    16, 0, 0);                                                   \
            }                                                                    \
        }
    #define LOAD_B(step, r0, r1)                                                 \
        {                                                                        \
            const float* wp_ = b_src + (size_t)(step) * 32 * 4096;               \
            r0 = *(const float4*)wp_;                                            \
            r1 = *(const float4*)(wp_ + 4096);                                   \
        }
    #define WRITE_B(buf, r0, r1)                                                 \
        {                                                                        \
            Bs[buf][bc8 * 4 + 0][bkp] = packbf2(r0.x, r1.x);                     \
            Bs[buf][bc8 * 4 + 1][bkp] = packbf2(r0.y, r1.y);                     \
            Bs[buf][bc8 * 4 + 2][bkp] = packbf2(r0.z, r1.z);                     \
            Bs[buf][bc8 * 4 + 3][bkp] = packbf2(r0.w, r1.w);                     \
        }
    #define COMPUTE(abuf, bbuf)                                                  \
        {                                                                        \
            short8 a_[4], b_[4];                                                 \
            _Pragma("unroll")                                                    \
            for (int mi = 0; mi < 4; ++mi)                                       \
                a_[mi] = *(const short8*)&As[abuf][ap_off[mi]];                  \
            _Pragma("unroll")                                                    \
            for (int ni = 0; ni < 4; ++ni) {                                     \
                int nr_ = ni * 16 + l15;                                         \
                union { uint2 u[2]; short8 v; } bb_;                             \
                bb_.u[0] = *(const uint2*)&Bs[bbuf][nr_][lk * 4];                \
                bb_.u[1] = *(const uint2*)&Bs[bbuf][nr_][lk * 4 + 2];            \
                b_[ni] = bb_.v;                                                  \
            }                                                                    \
            __builtin_amdgcn_s_setprio(1);                                       \
            _Pragma("unroll")                                                    \
            for (int mi = 0; mi < 4; ++mi)                                       \
                _Pragma("unroll")                                                \
                for (int ni = 0; ni < 4; ++ni)                                   \
                    acc[mi][ni] = __builtin_amdgcn_mfma_f32_16x16x32_bf16(       \
                        a_[mi], b_[ni], acc[mi][ni], 0, 0, 0);                   \
            __builtin_amdgcn_s_setprio(0);                                       \
        }
    #define VMCNT(n) __builtin_amdgcn_sched_barrier(0);                          \
                     asm volatile("s_waitcnt vmcnt(" #n ")" ::: "memory");       \
                     __builtin_amdgcn_sched_barrier(0)
    #define LGKM0    asm volatile("s_waitcnt lgkmcnt(0)" ::: "memory");          \
                     __builtin_amdgcn_sched_barrier(0)
    #define STEP(jA, abufI, jB, ldS0, ldS1, cA, cB, wB, wS0, wS1, VM)            \
        ISSUE_A(jA, abufI);                                                      \
        LOAD_B(jB, ldS0, ldS1);                                                  \
        COMPUTE(cA, cB);                                                         \
        VMCNT(VM);                                                               \
        WRITE_B(wB, wS0, wS1);                                                   \
        LGKM0;                                                                   \
        __builtin_amdgcn_s_barrier();

    float4 s0a, s0b, s1a, s1b, s2a, s2b;

    // ---- prologue ----
    ISSUE_A(0, 0);
    LOAD_B(0, s0a, s0b);
    ISSUE_A(1, 1);
    LOAD_B(1, s1a, s1b);
    LOAD_B(2, s2a, s2b);
    VMCNT(8);
    WRITE_B(0, s0a, s0b);
    LGKM0;
    __builtin_amdgcn_s_barrier();

    // ---- steady: iters 0..59, unrolled by 6 ----
    for (int j = 0; j < 60; j += 6) {
        STEP(j + 2, 2, j + 3, s0a, s0b, 0, 0, 1, s1a, s1b, 8)
        STEP(j + 3, 0, j + 4, s1a, s1b, 1, 1, 0, s2a, s2b, 8)
        STEP(j + 4, 1, j + 5, s2a, s2b, 2, 0, 1, s0a, s0b, 8)
        STEP(j + 5, 2, j + 6, s0a, s0b, 0, 1, 0, s1a, s1b, 8)
        STEP(j + 6, 0, j + 7, s1a, s1b, 1, 0, 1, s2a, s2b, 8)
        STEP(j + 7, 1, j + 8, s2a, s2b, 2, 1, 0, s0a, s0b, 8)
    }
    // ---- iter 60 ----
    STEP(62, 2, 63, s0a, s0b, 0, 0, 1, s1a, s1b, 8)
    // ---- iter 61 (drain) ----
    ISSUE_A(63, 0);
    COMPUTE(1, 1);
    VMCNT(6);
    WRITE_B(0, s2a, s2b);
    LGKM0;
    __builtin_amdgcn_s_barrier();
    // ---- iter 62 ----
    COMPUTE(2, 0);
    VMCNT(4);
    WRITE_B(1, s0a, s0b);
    LGKM0;
    __builtin_amdgcn_s_barrier();
    // ---- iter 63 ----
    VMCNT(0);
    COMPUTE(0, 1);

    #undef ISSUE_A
    #undef LOAD_B
    #undef WRITE_B
    #undef COMPUTE
    #undef VMCNT
    #undef LGKM0
    #undef STEP

    float* dst = parts + (size_t)s * (256 * 4096);
    #pragma unroll
    for (int mi = 0; mi < 4; ++mi) {
        #pragma unroll
        for (int ni = 0; ni < 4; ++ni) {
            int col = n0 + ni * 16 + l15;
            #pragma unroll
            for (int r = 0; r < 4; ++r) {
                int row = wave * 64 + mi * 16 + lk * 4 + r;
                dst[(size_t)row * 4096 + col] = acc[mi][ni][r];
            }
        }
    }
}

// ---- reduce partials + bias -> d_out ---------------------------------------
__global__ __launch_bounds__(256) void k_reduce(const float* __restrict__ parts,
                                                const float* __restrict__ linb,
                                                float* __restrict__ out) {
    int idx = blockIdx.x * 256 + threadIdx.x;
    float v = linb[idx & 4095];
    #pragma unroll
    for (int s = 0; s < 8; ++s) v += parts[(size_t)s * (256 * 4096) + idx];
    out[idx] = v;
}

extern "C" void kernel_launch(void* const* d_in, const int* in_sizes, int n_in,
                              void* d_out, int out_size, void* d_ws, size_t ws_size,
                              hipStream_t stream) {
    (void)in_sizes; (void)n_in; (void)out_size; (void)ws_size;
    const float* x   = (const float*)d_in[0];
    const int*   ei  = (const int*)d_in[1];
    const float* ea  = (const float*)d_in[2];
    /* d_in[3] = batch (unused, fixed layout) */
    const float* Wl  = (const float*)d_in[4];
    const float* Wr  = (const float*)d_in[5];
    const float* We  = (const float*)d_in[6];
    const float* att = (const float*)d_in[7];
    const float* bg  = (const float*)d_in[8];
    const float* W   = (const float*)d_in[9];
    const float* lb  = (const float*)d_in[10];
    float* out = (float*)d_out;

    char* p = (char*)d_ws;
    unsigned short* hb  = (unsigned short*)p; p += 8388608;            // 16384x256 bf16
    float* parts        = (float*)p;          p += 33554432;           // 8x256x4096 f32
    float* eapart       = (float*)p;          p += 16384;              // 256x16

    k_ea_part<<<256,  256, 0, stream>>>(ea, eapart);
    k_attn   <<<1024, 256, 0, stream>>>(ei, ea, eapart, att, We, x, Wl, Wr, bg, hb);
    k_gemm   <<<512,  256, 0, stream>>>(hb, W, parts);
    k_reduce <<<4096, 256, 0, stream>>>(parts, lb, out);
}